// Round 1
// baseline (911.562 us; speedup 1.0000x reference)
//
#include <hip/hip_runtime.h>
#include <cstdint>
#include <cstddef>

#define N_NODES 100000
#define N_EDGES 1600000
#define E_TOT   (N_EDGES + N_NODES)
#define F_IN    512
#define HEADS   8
#define HID     8
#define F_H     64          // HEADS*HID
#define NC      40
#define NEG     0.2f

// ---------------------------------------------------------------------------
// edge_index dtype probe: if stored as int64, every odd int32 word (high word)
// of the first 256 entries is 0. Writes flag=1 for int64, 0 for int32.
// ---------------------------------------------------------------------------
__global__ void k_detect(const int* __restrict__ ei, int* __restrict__ flag) {
  if (threadIdx.x == 0 && blockIdx.x == 0) {
    int nz = 0;
    for (int i = 0; i < 256; ++i) nz |= ei[2 * i + 1];
    *flag = (nz == 0) ? 1 : 0;
  }
}

// ---------------------------------------------------------------------------
// CSR build: histogram of dst (edges + self loops)
// ---------------------------------------------------------------------------
__global__ __launch_bounds__(256) void k_hist(const int* __restrict__ ei,
                                              const int* __restrict__ flag,
                                              int* __restrict__ deg) {
  int i = blockIdx.x * 256 + threadIdx.x;
  if (i >= E_TOT) return;
  int d;
  if (i < N_EDGES) {
    d = (*flag) ? ei[2 * (N_EDGES + i)] : ei[N_EDGES + i];
  } else {
    d = i - N_EDGES;
  }
  atomicAdd(&deg[d], 1);
}

// block-level exclusive scan (Hillis-Steele), 256/block
__global__ __launch_bounds__(256) void k_scanA(const int* __restrict__ deg,
                                               int* __restrict__ part,
                                               int* __restrict__ bsum) {
  __shared__ int sh[256];
  int i = blockIdx.x * 256 + threadIdx.x;
  int v = (i < N_NODES) ? deg[i] : 0;
  sh[threadIdx.x] = v;
  __syncthreads();
  for (int d = 1; d < 256; d <<= 1) {
    int t2 = (threadIdx.x >= d) ? sh[threadIdx.x - d] : 0;
    __syncthreads();
    sh[threadIdx.x] += t2;
    __syncthreads();
  }
  if (i < N_NODES) part[i] = sh[threadIdx.x] - v;   // exclusive
  if (threadIdx.x == 255) bsum[blockIdx.x] = sh[255];
}

#define NBLK_SCAN 391   // ceil(100000/256)

__global__ __launch_bounds__(512) void k_scanB(int* __restrict__ bsum) {
  __shared__ int sh[512];
  int v = (threadIdx.x < NBLK_SCAN) ? bsum[threadIdx.x] : 0;
  sh[threadIdx.x] = v;
  __syncthreads();
  for (int d = 1; d < 512; d <<= 1) {
    int t2 = (threadIdx.x >= d) ? sh[threadIdx.x - d] : 0;
    __syncthreads();
    sh[threadIdx.x] += t2;
    __syncthreads();
  }
  if (threadIdx.x < NBLK_SCAN) bsum[threadIdx.x] = sh[threadIdx.x] - v; // exclusive
}

__global__ __launch_bounds__(256) void k_scanC(const int* __restrict__ part,
                                               const int* __restrict__ bsum,
                                               int* __restrict__ rowstart,
                                               int* __restrict__ cursor) {
  int i = blockIdx.x * 256 + threadIdx.x;
  if (i < N_NODES) {
    int v = part[i] + bsum[blockIdx.x];
    rowstart[i] = v;
    cursor[i] = v;
  }
  if (i == 0) rowstart[N_NODES] = E_TOT;
}

__global__ __launch_bounds__(256) void k_fill(const int* __restrict__ ei,
                                              const int* __restrict__ flag,
                                              int* __restrict__ cursor,
                                              int* __restrict__ csrc) {
  int i = blockIdx.x * 256 + threadIdx.x;
  if (i >= E_TOT) return;
  int s, d;
  if (i < N_EDGES) {
    if (*flag) { s = ei[2 * i]; d = ei[2 * (N_EDGES + i)]; }
    else       { s = ei[i];     d = ei[N_EDGES + i]; }
  } else {
    s = d = i - N_EDGES;
  }
  int pos = atomicAdd(&cursor[d], 1);
  csrc[pos] = s;
}

// ---------------------------------------------------------------------------
// GEMM1: h1 = x @ W1  (100000x512 @ 512x64), fused attention logits.
// Block = 256 thr = 4 waves; block tile 128 rows x 64 cols.
// Wave (g,half): rows g*64+lane, cols half*32..+31.
// x staged in LDS (pitch 68 -> conflict-free per-lane row reads);
// W via wave-uniform pointer (readfirstlane) -> scalar loads.
// ---------------------------------------------------------------------------
__global__ __launch_bounds__(256) void k_gemm1(
    const float* __restrict__ x, const float* __restrict__ W1,
    const float* __restrict__ a_src, const float* __restrict__ a_dst,
    float* __restrict__ h1, float* __restrict__ als, float* __restrict__ ald) {
  constexpr int BM = 128, KC = 64, PITCH = 68;
  __shared__ float xs[BM * PITCH];
  const int t = threadIdx.x;
  const int lane = t & 63;
  const int w = t >> 6;
  const int g = w >> 1;
  const int half = w & 1;
  const int cb = __builtin_amdgcn_readfirstlane(half * 32);
  const int rb = blockIdx.x * BM;
  const int row = rb + g * 64 + lane;
  float acc[32];
#pragma unroll
  for (int i = 0; i < 32; ++i) acc[i] = 0.f;

  const int r0 = t >> 4;   // 0..15
  const int c4 = t & 15;   // col group of 4 floats
  for (int kc = 0; kc < F_IN; kc += KC) {
    __syncthreads();
#pragma unroll
    for (int i = 0; i < 8; ++i) {
      int r = r0 + i * 16;
      int gr = rb + r;
      float4 v = make_float4(0.f, 0.f, 0.f, 0.f);
      if (gr < N_NODES)
        v = *reinterpret_cast<const float4*>(&x[(size_t)gr * F_IN + kc + c4 * 4]);
      *reinterpret_cast<float4*>(&xs[r * PITCH + c4 * 4]) = v;
    }
    __syncthreads();
    const float* wbase = W1 + (size_t)kc * F_H + cb;
    const int lbase = (g * 64 + lane) * PITCH;
#pragma unroll 4
    for (int k4 = 0; k4 < KC / 4; ++k4) {
      float4 xv = *reinterpret_cast<const float4*>(&xs[lbase + k4 * 4]);
      const float xa[4] = {xv.x, xv.y, xv.z, xv.w};
#pragma unroll
      for (int j = 0; j < 4; ++j) {
        const float* wr = wbase + (size_t)(k4 * 4 + j) * F_H;
        const float xj = xa[j];
#pragma unroll
        for (int c = 0; c < 32; ++c) acc[c] += xj * wr[c];
      }
    }
  }
  if (row < N_NODES) {
    float4* hp = reinterpret_cast<float4*>(&h1[(size_t)row * F_H + cb]);
#pragma unroll
    for (int i = 0; i < 8; ++i)
      hp[i] = make_float4(acc[i * 4], acc[i * 4 + 1], acc[i * 4 + 2], acc[i * 4 + 3]);
    float s4[4], d4[4];
#pragma unroll
    for (int hh = 0; hh < 4; ++hh) {
      int head = (cb >> 3) + hh;
      float s = 0.f, d = 0.f;
#pragma unroll
      for (int f = 0; f < 8; ++f) {
        float hv = acc[hh * 8 + f];
        s += hv * a_src[head * 8 + f];
        d += hv * a_dst[head * 8 + f];
      }
      s4[hh] = s; d4[hh] = d;
    }
    *reinterpret_cast<float4*>(&als[(size_t)row * HEADS + (cb >> 3)]) =
        make_float4(s4[0], s4[1], s4[2], s4[3]);
    *reinterpret_cast<float4*>(&ald[(size_t)row * HEADS + (cb >> 3)]) =
        make_float4(d4[0], d4[1], d4[2], d4[3]);
  }
}

// ---------------------------------------------------------------------------
// Layer-1 edge softmax + aggregation + bias + ELU. One wave per node,
// lane = output feature (head = lane>>3). Pull over CSR; numerator and
// denominator accumulated together, divide once.
// ---------------------------------------------------------------------------
__global__ __launch_bounds__(256) void k_agg1(
    const int* __restrict__ rowstart, const int* __restrict__ csrc,
    const float* __restrict__ h1, const float* __restrict__ als,
    const float* __restrict__ ald, const float* __restrict__ b1,
    float* __restrict__ hact) {
  int wid = (int)((blockIdx.x * 256 + threadIdx.x) >> 6);
  int lane = threadIdx.x & 63;
  if (wid >= N_NODES) return;
  const int n = wid;
  const int e0 = rowstart[n], e1 = rowstart[n + 1];
  const int hh = lane >> 3;
  const float aldv = ald[(size_t)n * HEADS + hh];

  float m = -1e30f;
  for (int e = e0; e < e1; ++e) {
    int s = csrc[e];
    float v = als[(size_t)s * HEADS + hh] + aldv;
    v = (v > 0.f) ? v : NEG * v;
    m = fmaxf(m, v);
  }
  float denom = 0.f, acc = 0.f;
  for (int e = e0; e < e1; ++e) {
    int s = csrc[e];
    float v = als[(size_t)s * HEADS + hh] + aldv;
    v = (v > 0.f) ? v : NEG * v;
    float p = __expf(v - m);
    denom += p;
    acc += p * h1[(size_t)s * F_H + lane];
  }
  float o = acc / denom + b1[lane];
  o = (o > 0.f) ? o : expm1f(o);
  hact[(size_t)n * F_H + lane] = o;
}

// ---------------------------------------------------------------------------
// Layer-2 projection: h2 = hact @ W2 (64x40) + attention logits (1 head).
// Block: 256 threads, 64 nodes; thread = (node, class-group of 10).
// ---------------------------------------------------------------------------
__global__ __launch_bounds__(256) void k_l2proj(
    const float* __restrict__ hact, const float* __restrict__ W2,
    const float* __restrict__ a_src2, const float* __restrict__ a_dst2,
    float* __restrict__ h2, float* __restrict__ als2, float* __restrict__ ald2) {
  __shared__ float hs[64 * 68];
  __shared__ float w2s[F_H * NC];
  const int t = threadIdx.x;
  const int nb = blockIdx.x * 64;
  {
    int r0 = t >> 4, c4 = t & 15;
#pragma unroll
    for (int i = 0; i < 4; ++i) {
      int r = r0 + i * 16;
      int gr = nb + r;
      float4 v = make_float4(0.f, 0.f, 0.f, 0.f);
      if (gr < N_NODES)
        v = *reinterpret_cast<const float4*>(&hact[(size_t)gr * F_H + c4 * 4]);
      *reinterpret_cast<float4*>(&hs[r * 68 + c4 * 4]) = v;
    }
  }
  for (int i = t; i < F_H * NC; i += 256) w2s[i] = W2[i];
  __syncthreads();

  const int node = t >> 2, cg = t & 3;
  float acc[10];
#pragma unroll
  for (int c = 0; c < 10; ++c) acc[c] = 0.f;
  for (int k = 0; k < F_H; ++k) {
    float xv = hs[node * 68 + k];
#pragma unroll
    for (int c = 0; c < 10; ++c) acc[c] += xv * w2s[k * NC + cg * 10 + c];
  }
  const int gn = nb + node;
  float ps = 0.f, pd = 0.f;
#pragma unroll
  for (int c = 0; c < 10; ++c) {
    ps += acc[c] * a_src2[cg * 10 + c];
    pd += acc[c] * a_dst2[cg * 10 + c];
  }
  ps += __shfl_xor(ps, 1); ps += __shfl_xor(ps, 2);
  pd += __shfl_xor(pd, 1); pd += __shfl_xor(pd, 2);
  if (gn < N_NODES) {
#pragma unroll
    for (int c = 0; c < 10; ++c) h2[(size_t)gn * NC + cg * 10 + c] = acc[c];
    if (cg == 0) { als2[gn] = ps; ald2[gn] = pd; }
  }
}

// ---------------------------------------------------------------------------
// Layer-2 edge softmax + aggregation + bias + log_softmax. Wave per node.
// ---------------------------------------------------------------------------
__global__ __launch_bounds__(256) void k_agg2(
    const int* __restrict__ rowstart, const int* __restrict__ csrc,
    const float* __restrict__ h2, const float* __restrict__ als2,
    const float* __restrict__ ald2, const float* __restrict__ b2,
    float* __restrict__ out) {
  int wid = (int)((blockIdx.x * 256 + threadIdx.x) >> 6);
  int lane = threadIdx.x & 63;
  if (wid >= N_NODES) return;
  const int n = wid;
  const int e0 = rowstart[n], e1 = rowstart[n + 1];
  const float aldv = ald2[n];

  float m = -1e30f;
  for (int e = e0; e < e1; ++e) {
    float v = als2[csrc[e]] + aldv;
    v = (v > 0.f) ? v : NEG * v;
    m = fmaxf(m, v);
  }
  float denom = 0.f, acc = 0.f;
  for (int e = e0; e < e1; ++e) {
    int s = csrc[e];
    float v = als2[s] + aldv;
    v = (v > 0.f) ? v : NEG * v;
    float p = __expf(v - m);
    denom += p;
    if (lane < NC) acc += p * h2[(size_t)s * NC + lane];
  }
  float o = (lane < NC) ? (acc / denom + b2[lane]) : -1e30f;
  float mx = o;
#pragma unroll
  for (int d = 1; d < 64; d <<= 1) mx = fmaxf(mx, __shfl_xor(mx, d));
  float ex = (lane < NC) ? __expf(o - mx) : 0.f;
  float se = ex;
#pragma unroll
  for (int d = 1; d < 64; d <<= 1) se += __shfl_xor(se, d);
  if (lane < NC) out[(size_t)n * NC + lane] = (o - mx) - __logf(se);
}

// ---------------------------------------------------------------------------
extern "C" void kernel_launch(void* const* d_in, const int* in_sizes, int n_in,
                              void* d_out, int out_size, void* d_ws, size_t ws_size,
                              hipStream_t stream) {
  const float* x      = (const float*)d_in[0];
  const int*   ei     = (const int*)d_in[1];
  const float* W1     = (const float*)d_in[2];
  const float* a_src1 = (const float*)d_in[3];
  const float* a_dst1 = (const float*)d_in[4];
  const float* b1     = (const float*)d_in[5];
  const float* W2     = (const float*)d_in[6];
  const float* a_src2 = (const float*)d_in[7];
  const float* a_dst2 = (const float*)d_in[8];
  const float* b2     = (const float*)d_in[9];
  float* out = (float*)d_out;

  char* ws = (char*)d_ws;
  size_t o = 0;
  auto carve = [&](size_t bytes) -> char* {
    char* p = ws + o;
    o = (o + bytes + 255) & ~(size_t)255;
    return p;
  };
  int*   deg      = (int*)carve((size_t)N_NODES * 4);
  int*   part     = (int*)carve((size_t)N_NODES * 4);
  int*   bsum     = (int*)carve(2048);
  int*   rowstart = (int*)carve((size_t)(N_NODES + 1) * 4);
  int*   cursor   = (int*)carve((size_t)N_NODES * 4);
  int*   csrc     = (int*)carve((size_t)E_TOT * 4);
  int*   flag     = (int*)carve(256);
  float* h1       = (float*)carve((size_t)N_NODES * F_H * 4);
  float* als1     = (float*)carve((size_t)N_NODES * HEADS * 4);
  float* ald1     = (float*)carve((size_t)N_NODES * HEADS * 4);
  float* hact     = (float*)carve((size_t)N_NODES * F_H * 4);
  float* h2       = (float*)carve((size_t)N_NODES * NC * 4);
  float* als2     = (float*)carve((size_t)N_NODES * 4);
  float* ald2     = (float*)carve((size_t)N_NODES * 4);
  (void)ws_size; (void)n_in; (void)in_sizes; (void)out_size;

  hipMemsetAsync(deg, 0, (size_t)N_NODES * 4, stream);
  k_detect<<<1, 64, 0, stream>>>(ei, flag);

  const int egrid = (E_TOT + 255) / 256;
  k_hist<<<egrid, 256, 0, stream>>>(ei, flag, deg);
  k_scanA<<<NBLK_SCAN, 256, 0, stream>>>(deg, part, bsum);
  k_scanB<<<1, 512, 0, stream>>>(bsum);
  k_scanC<<<NBLK_SCAN, 256, 0, stream>>>(part, bsum, rowstart, cursor);
  k_fill<<<egrid, 256, 0, stream>>>(ei, flag, cursor, csrc);

  k_gemm1<<<(N_NODES + 127) / 128, 256, 0, stream>>>(x, W1, a_src1, a_dst1, h1, als1, ald1);
  k_agg1<<<(N_NODES * 64 + 255) / 256, 256, 0, stream>>>(rowstart, csrc, h1, als1, ald1, b1, hact);
  k_l2proj<<<(N_NODES + 63) / 64, 256, 0, stream>>>(hact, W2, a_src2, a_dst2, h2, als2, ald2);
  k_agg2<<<(N_NODES * 64 + 255) / 256, 256, 0, stream>>>(rowstart, csrc, h2, als2, ald2, b2, out);
}

// Round 2
// 541.282 us; speedup vs baseline: 1.6841x; 1.6841x over previous
//
#include <hip/hip_runtime.h>
#include <cstdint>
#include <cstddef>

#define N_NODES 100000
#define N_EDGES 1600000
#define E_TOT   (N_EDGES + N_NODES)
#define F_IN    512
#define HEADS   8
#define HID     8
#define F_H     64          // HEADS*HID
#define NC      40
#define NEG     0.2f

// ---------------------------------------------------------------------------
// edge_index dtype probe: if stored as int64, every odd int32 word (high word)
// of the first 256 entries is 0. Writes flag=1 for int64, 0 for int32.
// ---------------------------------------------------------------------------
__global__ void k_detect(const int* __restrict__ ei, int* __restrict__ flag) {
  if (threadIdx.x == 0 && blockIdx.x == 0) {
    int nz = 0;
    for (int i = 0; i < 256; ++i) nz |= ei[2 * i + 1];
    *flag = (nz == 0) ? 1 : 0;
  }
}

// ---------------------------------------------------------------------------
// CSR build: histogram of dst (edges + self loops)
// ---------------------------------------------------------------------------
__global__ __launch_bounds__(256) void k_hist(const int* __restrict__ ei,
                                              const int* __restrict__ flag,
                                              int* __restrict__ deg) {
  int i = blockIdx.x * 256 + threadIdx.x;
  if (i >= E_TOT) return;
  int d;
  if (i < N_EDGES) {
    d = (*flag) ? ei[2 * (N_EDGES + i)] : ei[N_EDGES + i];
  } else {
    d = i - N_EDGES;
  }
  atomicAdd(&deg[d], 1);
}

// block-level exclusive scan (Hillis-Steele), 256/block
__global__ __launch_bounds__(256) void k_scanA(const int* __restrict__ deg,
                                               int* __restrict__ part,
                                               int* __restrict__ bsum) {
  __shared__ int sh[256];
  int i = blockIdx.x * 256 + threadIdx.x;
  int v = (i < N_NODES) ? deg[i] : 0;
  sh[threadIdx.x] = v;
  __syncthreads();
  for (int d = 1; d < 256; d <<= 1) {
    int t2 = (threadIdx.x >= d) ? sh[threadIdx.x - d] : 0;
    __syncthreads();
    sh[threadIdx.x] += t2;
    __syncthreads();
  }
  if (i < N_NODES) part[i] = sh[threadIdx.x] - v;   // exclusive
  if (threadIdx.x == 255) bsum[blockIdx.x] = sh[255];
}

#define NBLK_SCAN 391   // ceil(100000/256)

__global__ __launch_bounds__(512) void k_scanB(int* __restrict__ bsum) {
  __shared__ int sh[512];
  int v = (threadIdx.x < NBLK_SCAN) ? bsum[threadIdx.x] : 0;
  sh[threadIdx.x] = v;
  __syncthreads();
  for (int d = 1; d < 512; d <<= 1) {
    int t2 = (threadIdx.x >= d) ? sh[threadIdx.x - d] : 0;
    __syncthreads();
    sh[threadIdx.x] += t2;
    __syncthreads();
  }
  if (threadIdx.x < NBLK_SCAN) bsum[threadIdx.x] = sh[threadIdx.x] - v; // exclusive
}

__global__ __launch_bounds__(256) void k_scanC(const int* __restrict__ part,
                                               const int* __restrict__ bsum,
                                               int* __restrict__ rowstart,
                                               int* __restrict__ cursor) {
  int i = blockIdx.x * 256 + threadIdx.x;
  if (i < N_NODES) {
    int v = part[i] + bsum[blockIdx.x];
    rowstart[i] = v;
    cursor[i] = v;
  }
  if (i == 0) rowstart[N_NODES] = E_TOT;
}

__global__ __launch_bounds__(256) void k_fill(const int* __restrict__ ei,
                                              const int* __restrict__ flag,
                                              int* __restrict__ cursor,
                                              int* __restrict__ csrc) {
  int i = blockIdx.x * 256 + threadIdx.x;
  if (i >= E_TOT) return;
  int s, d;
  if (i < N_EDGES) {
    if (*flag) { s = ei[2 * i]; d = ei[2 * (N_EDGES + i)]; }
    else       { s = ei[i];     d = ei[N_EDGES + i]; }
  } else {
    s = d = i - N_EDGES;
  }
  int pos = atomicAdd(&cursor[d], 1);
  csrc[pos] = s;
}

// ---------------------------------------------------------------------------
// GEMM1: h1 = x @ W1  (100000x512 @ 512x64), fused attention logits.
// Block = 256 thr = 4 waves; block tile 128 rows x 64 cols.
// Wave (g,half): rows g*64+lane, cols half*32..+31.
// x staged in LDS (pitch 68 -> conflict-free per-lane row reads);
// W via wave-uniform pointer (readfirstlane) -> scalar loads.
// ---------------------------------------------------------------------------
__global__ __launch_bounds__(256) void k_gemm1(
    const float* __restrict__ x, const float* __restrict__ W1,
    const float* __restrict__ a_src, const float* __restrict__ a_dst,
    float* __restrict__ h1, float* __restrict__ als, float* __restrict__ ald) {
  constexpr int BM = 128, KC = 64, PITCH = 68;
  __shared__ float xs[BM * PITCH];
  const int t = threadIdx.x;
  const int lane = t & 63;
  const int w = t >> 6;
  const int g = w >> 1;
  const int half = w & 1;
  const int cb = __builtin_amdgcn_readfirstlane(half * 32);
  const int rb = blockIdx.x * BM;
  const int row = rb + g * 64 + lane;
  float acc[32];
#pragma unroll
  for (int i = 0; i < 32; ++i) acc[i] = 0.f;

  const int r0 = t >> 4;   // 0..15
  const int c4 = t & 15;   // col group of 4 floats
  for (int kc = 0; kc < F_IN; kc += KC) {
    __syncthreads();
#pragma unroll
    for (int i = 0; i < 8; ++i) {
      int r = r0 + i * 16;
      int gr = rb + r;
      float4 v = make_float4(0.f, 0.f, 0.f, 0.f);
      if (gr < N_NODES)
        v = *reinterpret_cast<const float4*>(&x[(size_t)gr * F_IN + kc + c4 * 4]);
      *reinterpret_cast<float4*>(&xs[r * PITCH + c4 * 4]) = v;
    }
    __syncthreads();
    const float* wbase = W1 + (size_t)kc * F_H + cb;
    const int lbase = (g * 64 + lane) * PITCH;
#pragma unroll 4
    for (int k4 = 0; k4 < KC / 4; ++k4) {
      float4 xv = *reinterpret_cast<const float4*>(&xs[lbase + k4 * 4]);
      const float xa[4] = {xv.x, xv.y, xv.z, xv.w};
#pragma unroll
      for (int j = 0; j < 4; ++j) {
        const float* wr = wbase + (size_t)(k4 * 4 + j) * F_H;
        const float xj = xa[j];
#pragma unroll
        for (int c = 0; c < 32; ++c) acc[c] += xj * wr[c];
      }
    }
  }
  if (row < N_NODES) {
    float4* hp = reinterpret_cast<float4*>(&h1[(size_t)row * F_H + cb]);
#pragma unroll
    for (int i = 0; i < 8; ++i)
      hp[i] = make_float4(acc[i * 4], acc[i * 4 + 1], acc[i * 4 + 2], acc[i * 4 + 3]);
    float s4[4], d4[4];
#pragma unroll
    for (int hh = 0; hh < 4; ++hh) {
      int head = (cb >> 3) + hh;
      float s = 0.f, d = 0.f;
#pragma unroll
      for (int f = 0; f < 8; ++f) {
        float hv = acc[hh * 8 + f];
        s += hv * a_src[head * 8 + f];
        d += hv * a_dst[head * 8 + f];
      }
      s4[hh] = s; d4[hh] = d;
    }
    *reinterpret_cast<float4*>(&als[(size_t)row * HEADS + (cb >> 3)]) =
        make_float4(s4[0], s4[1], s4[2], s4[3]);
    *reinterpret_cast<float4*>(&ald[(size_t)row * HEADS + (cb >> 3)]) =
        make_float4(d4[0], d4[1], d4[2], d4[3]);
  }
}

// ---------------------------------------------------------------------------
// Layer-1 edge softmax + aggregation + bias + ELU. One wave per node,
// lane = output feature (head = lane>>3). Pull over CSR.
// SINGLE PASS: softmax shift-invariance lets us drop the max pass (logits are
// tiny: |v| < ~2, exp safe). Unrolled x4 so 4 independent gathers are in
// flight per wave.
// ---------------------------------------------------------------------------
__global__ __launch_bounds__(256) void k_agg1(
    const int* __restrict__ rowstart, const int* __restrict__ csrc,
    const float* __restrict__ h1, const float* __restrict__ als,
    const float* __restrict__ ald, const float* __restrict__ b1,
    float* __restrict__ hact) {
  int wid = (int)((blockIdx.x * 256 + threadIdx.x) >> 6);
  int lane = threadIdx.x & 63;
  if (wid >= N_NODES) return;
  const int n = wid;
  const int e0 = rowstart[n], e1 = rowstart[n + 1];
  const int hh = lane >> 3;
  const float aldv = ald[(size_t)n * HEADS + hh];

  float denom = 0.f, acc = 0.f;
  int e = e0;
  for (; e + 4 <= e1; e += 4) {
    int s0 = csrc[e], s1 = csrc[e + 1], s2 = csrc[e + 2], s3 = csrc[e + 3];
    float a0 = als[(size_t)s0 * HEADS + hh];
    float a1 = als[(size_t)s1 * HEADS + hh];
    float a2 = als[(size_t)s2 * HEADS + hh];
    float a3 = als[(size_t)s3 * HEADS + hh];
    float f0 = h1[(size_t)s0 * F_H + lane];
    float f1 = h1[(size_t)s1 * F_H + lane];
    float f2 = h1[(size_t)s2 * F_H + lane];
    float f3 = h1[(size_t)s3 * F_H + lane];
    float v0 = a0 + aldv; v0 = (v0 > 0.f) ? v0 : NEG * v0;
    float v1 = a1 + aldv; v1 = (v1 > 0.f) ? v1 : NEG * v1;
    float v2 = a2 + aldv; v2 = (v2 > 0.f) ? v2 : NEG * v2;
    float v3 = a3 + aldv; v3 = (v3 > 0.f) ? v3 : NEG * v3;
    float p0 = __expf(v0), p1 = __expf(v1), p2 = __expf(v2), p3 = __expf(v3);
    denom += (p0 + p1) + (p2 + p3);
    acc += p0 * f0 + p1 * f1 + p2 * f2 + p3 * f3;
  }
  for (; e < e1; ++e) {
    int s = csrc[e];
    float v = als[(size_t)s * HEADS + hh] + aldv;
    v = (v > 0.f) ? v : NEG * v;
    float p = __expf(v);
    denom += p;
    acc += p * h1[(size_t)s * F_H + lane];
  }
  float o = acc / denom + b1[lane];
  o = (o > 0.f) ? o : expm1f(o);
  hact[(size_t)n * F_H + lane] = o;
}

// ---------------------------------------------------------------------------
// Layer-2 projection: h2 = hact @ W2 (64x40) + attention logits (1 head).
// Block: 256 threads, 64 nodes; thread = (node, class-group of 10).
// ---------------------------------------------------------------------------
__global__ __launch_bounds__(256) void k_l2proj(
    const float* __restrict__ hact, const float* __restrict__ W2,
    const float* __restrict__ a_src2, const float* __restrict__ a_dst2,
    float* __restrict__ h2, float* __restrict__ als2, float* __restrict__ ald2) {
  __shared__ float hs[64 * 68];
  __shared__ float w2s[F_H * NC];
  const int t = threadIdx.x;
  const int nb = blockIdx.x * 64;
  {
    int r0 = t >> 4, c4 = t & 15;
#pragma unroll
    for (int i = 0; i < 4; ++i) {
      int r = r0 + i * 16;
      int gr = nb + r;
      float4 v = make_float4(0.f, 0.f, 0.f, 0.f);
      if (gr < N_NODES)
        v = *reinterpret_cast<const float4*>(&hact[(size_t)gr * F_H + c4 * 4]);
      *reinterpret_cast<float4*>(&hs[r * 68 + c4 * 4]) = v;
    }
  }
  for (int i = t; i < F_H * NC; i += 256) w2s[i] = W2[i];
  __syncthreads();

  const int node = t >> 2, cg = t & 3;
  float acc[10];
#pragma unroll
  for (int c = 0; c < 10; ++c) acc[c] = 0.f;
  for (int k = 0; k < F_H; ++k) {
    float xv = hs[node * 68 + k];
#pragma unroll
    for (int c = 0; c < 10; ++c) acc[c] += xv * w2s[k * NC + cg * 10 + c];
  }
  const int gn = nb + node;
  float ps = 0.f, pd = 0.f;
#pragma unroll
  for (int c = 0; c < 10; ++c) {
    ps += acc[c] * a_src2[cg * 10 + c];
    pd += acc[c] * a_dst2[cg * 10 + c];
  }
  ps += __shfl_xor(ps, 1); ps += __shfl_xor(ps, 2);
  pd += __shfl_xor(pd, 1); pd += __shfl_xor(pd, 2);
  if (gn < N_NODES) {
#pragma unroll
    for (int c = 0; c < 10; ++c) h2[(size_t)gn * NC + cg * 10 + c] = acc[c];
    if (cg == 0) { als2[gn] = ps; ald2[gn] = pd; }
  }
}

// ---------------------------------------------------------------------------
// Layer-2 edge softmax + aggregation + bias + log_softmax. Wave per node.
// Single pass (no max subtraction), unrolled x4.
// ---------------------------------------------------------------------------
__global__ __launch_bounds__(256) void k_agg2(
    const int* __restrict__ rowstart, const int* __restrict__ csrc,
    const float* __restrict__ h2, const float* __restrict__ als2,
    const float* __restrict__ ald2, const float* __restrict__ b2,
    float* __restrict__ out) {
  int wid = (int)((blockIdx.x * 256 + threadIdx.x) >> 6);
  int lane = threadIdx.x & 63;
  if (wid >= N_NODES) return;
  const int n = wid;
  const int e0 = rowstart[n], e1 = rowstart[n + 1];
  const float aldv = ald2[n];
  const bool act = (lane < NC);
  const int fl = act ? lane : 0;

  float denom = 0.f, acc = 0.f;
  int e = e0;
  for (; e + 4 <= e1; e += 4) {
    int s0 = csrc[e], s1 = csrc[e + 1], s2 = csrc[e + 2], s3 = csrc[e + 3];
    float a0 = als2[s0], a1 = als2[s1], a2 = als2[s2], a3 = als2[s3];
    float f0 = h2[(size_t)s0 * NC + fl];
    float f1 = h2[(size_t)s1 * NC + fl];
    float f2 = h2[(size_t)s2 * NC + fl];
    float f3 = h2[(size_t)s3 * NC + fl];
    float v0 = a0 + aldv; v0 = (v0 > 0.f) ? v0 : NEG * v0;
    float v1 = a1 + aldv; v1 = (v1 > 0.f) ? v1 : NEG * v1;
    float v2 = a2 + aldv; v2 = (v2 > 0.f) ? v2 : NEG * v2;
    float v3 = a3 + aldv; v3 = (v3 > 0.f) ? v3 : NEG * v3;
    float p0 = __expf(v0), p1 = __expf(v1), p2 = __expf(v2), p3 = __expf(v3);
    denom += (p0 + p1) + (p2 + p3);
    acc += p0 * f0 + p1 * f1 + p2 * f2 + p3 * f3;
  }
  for (; e < e1; ++e) {
    int s = csrc[e];
    float v = als2[s] + aldv;
    v = (v > 0.f) ? v : NEG * v;
    float p = __expf(v);
    denom += p;
    acc += p * h2[(size_t)s * NC + fl];
  }
  float o = act ? (acc / denom + b2[lane]) : -1e30f;
  float mx = o;
#pragma unroll
  for (int d = 1; d < 64; d <<= 1) mx = fmaxf(mx, __shfl_xor(mx, d));
  float ex = act ? __expf(o - mx) : 0.f;
  float se = ex;
#pragma unroll
  for (int d = 1; d < 64; d <<= 1) se += __shfl_xor(se, d);
  if (act) out[(size_t)n * NC + lane] = (o - mx) - __logf(se);
}

// ---------------------------------------------------------------------------
extern "C" void kernel_launch(void* const* d_in, const int* in_sizes, int n_in,
                              void* d_out, int out_size, void* d_ws, size_t ws_size,
                              hipStream_t stream) {
  const float* x      = (const float*)d_in[0];
  const int*   ei     = (const int*)d_in[1];
  const float* W1     = (const float*)d_in[2];
  const float* a_src1 = (const float*)d_in[3];
  const float* a_dst1 = (const float*)d_in[4];
  const float* b1     = (const float*)d_in[5];
  const float* W2     = (const float*)d_in[6];
  const float* a_src2 = (const float*)d_in[7];
  const float* a_dst2 = (const float*)d_in[8];
  const float* b2     = (const float*)d_in[9];
  float* out = (float*)d_out;

  char* ws = (char*)d_ws;
  size_t o = 0;
  auto carve = [&](size_t bytes) -> char* {
    char* p = ws + o;
    o = (o + bytes + 255) & ~(size_t)255;
    return p;
  };
  int*   deg      = (int*)carve((size_t)N_NODES * 4);
  int*   part     = (int*)carve((size_t)N_NODES * 4);
  int*   bsum     = (int*)carve(2048);
  int*   rowstart = (int*)carve((size_t)(N_NODES + 1) * 4);
  int*   cursor   = (int*)carve((size_t)N_NODES * 4);
  int*   csrc     = (int*)carve((size_t)E_TOT * 4);
  int*   flag     = (int*)carve(256);
  float* h1       = (float*)carve((size_t)N_NODES * F_H * 4);
  float* als1     = (float*)carve((size_t)N_NODES * HEADS * 4);
  float* ald1     = (float*)carve((size_t)N_NODES * HEADS * 4);
  float* hact     = (float*)carve((size_t)N_NODES * F_H * 4);
  float* h2       = (float*)carve((size_t)N_NODES * NC * 4);
  float* als2     = (float*)carve((size_t)N_NODES * 4);
  float* ald2     = (float*)carve((size_t)N_NODES * 4);
  (void)ws_size; (void)n_in; (void)in_sizes; (void)out_size;

  hipMemsetAsync(deg, 0, (size_t)N_NODES * 4, stream);
  k_detect<<<1, 64, 0, stream>>>(ei, flag);

  const int egrid = (E_TOT + 255) / 256;
  k_hist<<<egrid, 256, 0, stream>>>(ei, flag, deg);
  k_scanA<<<NBLK_SCAN, 256, 0, stream>>>(deg, part, bsum);
  k_scanB<<<1, 512, 0, stream>>>(bsum);
  k_scanC<<<NBLK_SCAN, 256, 0, stream>>>(part, bsum, rowstart, cursor);
  k_fill<<<egrid, 256, 0, stream>>>(ei, flag, cursor, csrc);

  k_gemm1<<<(N_NODES + 127) / 128, 256, 0, stream>>>(x, W1, a_src1, a_dst1, h1, als1, ald1);
  k_agg1<<<(N_NODES * 64 + 255) / 256, 256, 0, stream>>>(rowstart, csrc, h1, als1, ald1, b1, hact);
  k_l2proj<<<(N_NODES + 63) / 64, 256, 0, stream>>>(hact, W2, a_src2, a_dst2, h2, als2, ald2);
  k_agg2<<<(N_NODES * 64 + 255) / 256, 256, 0, stream>>>(rowstart, csrc, h2, als2, ald2, b2, out);
}

// Round 3
// 487.349 us; speedup vs baseline: 1.8704x; 1.1107x over previous
//
#include <hip/hip_runtime.h>
#include <hip/hip_bf16.h>
#include <cstdint>
#include <cstddef>

#define N_NODES 100000
#define N_EDGES 1600000
#define E_TOT   (N_EDGES + N_NODES)
#define F_IN    512
#define HEADS   8
#define HID     8
#define F_H     64          // HEADS*HID
#define NC      40
#define NEG     0.2f

typedef __attribute__((ext_vector_type(8))) __bf16 bf16x8;
typedef __attribute__((ext_vector_type(4))) float f32x4;
typedef __attribute__((ext_vector_type(8))) unsigned short u16x8;

// ---------------------------------------------------------------------------
// edge_index dtype probe: int64 -> every odd int32 word of first entries is 0.
// ---------------------------------------------------------------------------
__global__ void k_detect(const int* __restrict__ ei, int* __restrict__ flag) {
  if (threadIdx.x == 0 && blockIdx.x == 0) {
    int nz = 0;
    for (int i = 0; i < 256; ++i) nz |= ei[2 * i + 1];
    *flag = (nz == 0) ? 1 : 0;
  }
}

// ---------------------------------------------------------------------------
// CSR build
// ---------------------------------------------------------------------------
__global__ __launch_bounds__(256) void k_hist(const int* __restrict__ ei,
                                              const int* __restrict__ flag,
                                              int* __restrict__ deg) {
  int i = blockIdx.x * 256 + threadIdx.x;
  if (i >= E_TOT) return;
  int d;
  if (i < N_EDGES) {
    d = (*flag) ? ei[2 * (N_EDGES + i)] : ei[N_EDGES + i];
  } else {
    d = i - N_EDGES;
  }
  atomicAdd(&deg[d], 1);
}

__global__ __launch_bounds__(256) void k_scanA(const int* __restrict__ deg,
                                               int* __restrict__ part,
                                               int* __restrict__ bsum) {
  __shared__ int sh[256];
  int i = blockIdx.x * 256 + threadIdx.x;
  int v = (i < N_NODES) ? deg[i] : 0;
  sh[threadIdx.x] = v;
  __syncthreads();
  for (int d = 1; d < 256; d <<= 1) {
    int t2 = (threadIdx.x >= d) ? sh[threadIdx.x - d] : 0;
    __syncthreads();
    sh[threadIdx.x] += t2;
    __syncthreads();
  }
  if (i < N_NODES) part[i] = sh[threadIdx.x] - v;   // exclusive
  if (threadIdx.x == 255) bsum[blockIdx.x] = sh[255];
}

#define NBLK_SCAN 391   // ceil(100000/256)

__global__ __launch_bounds__(512) void k_scanB(int* __restrict__ bsum) {
  __shared__ int sh[512];
  int v = (threadIdx.x < NBLK_SCAN) ? bsum[threadIdx.x] : 0;
  sh[threadIdx.x] = v;
  __syncthreads();
  for (int d = 1; d < 512; d <<= 1) {
    int t2 = (threadIdx.x >= d) ? sh[threadIdx.x - d] : 0;
    __syncthreads();
    sh[threadIdx.x] += t2;
    __syncthreads();
  }
  if (threadIdx.x < NBLK_SCAN) bsum[threadIdx.x] = sh[threadIdx.x] - v; // exclusive
}

__global__ __launch_bounds__(256) void k_scanC(const int* __restrict__ part,
                                               const int* __restrict__ bsum,
                                               int* __restrict__ rowstart,
                                               int* __restrict__ cursor) {
  int i = blockIdx.x * 256 + threadIdx.x;
  if (i < N_NODES) {
    int v = part[i] + bsum[blockIdx.x];
    rowstart[i] = v;
    cursor[i] = v;
  }
  if (i == 0) rowstart[N_NODES] = E_TOT;
}

__global__ __launch_bounds__(256) void k_fill(const int* __restrict__ ei,
                                              const int* __restrict__ flag,
                                              int* __restrict__ cursor,
                                              int* __restrict__ csrc) {
  int i = blockIdx.x * 256 + threadIdx.x;
  if (i >= E_TOT) return;
  int s, d;
  if (i < N_EDGES) {
    if (*flag) { s = ei[2 * i]; d = ei[2 * (N_EDGES + i)]; }
    else       { s = ei[i];     d = ei[N_EDGES + i]; }
  } else {
    s = d = i - N_EDGES;
  }
  int pos = atomicAdd(&cursor[d], 1);
  csrc[pos] = s;
}

// ---------------------------------------------------------------------------
// W1 repack: fp32 (512x64) -> bf16 B-fragment-major for mfma_f32_16x16x32_bf16.
// Fragment (s,t,lane): 8 bf16 = W1[s*32 + (lane>>4)*8 + i][t*16 + (lane&15)],
// stored contiguously at w1f[(s*4+t)*64 + lane] (16B). 4096 frags = 64KB.
// ---------------------------------------------------------------------------
__global__ __launch_bounds__(256) void k_packW(const float* __restrict__ W1,
                                               uint4* __restrict__ w1f) {
  int tid = blockIdx.x * 256 + threadIdx.x;   // 0..4095
  if (tid >= 4096) return;
  int lane = tid & 63;
  int t = (tid >> 6) & 3;
  int s = tid >> 8;
  int k0 = s * 32 + ((lane >> 4) << 3);
  int col = t * 16 + (lane & 15);
  unsigned short u[8];
#pragma unroll
  for (int i = 0; i < 8; ++i) {
    __hip_bfloat16 b = __float2bfloat16(W1[(size_t)(k0 + i) * F_H + col]);
    u[i] = __builtin_bit_cast(unsigned short, b);
  }
  u16x8 v;
#pragma unroll
  for (int i = 0; i < 8; ++i) v[i] = u[i];
  w1f[tid] = __builtin_bit_cast(uint4, v);
}

// ---------------------------------------------------------------------------
// GEMM1 via MFMA: h1 = bf16(x) @ bf16(W1), fp32 accumulate.
// Block 256 = 4 waves; wave owns 16 rows x 64 cols. No LDS, no barriers.
// A frag: row = lane&15, k = (lane>>4)*8+i (8 contiguous fp32 -> cvt bf16).
// D frag: col = lane&15, row = (lane>>4)*4+reg  [measured: learn_hip m89].
// ---------------------------------------------------------------------------
__global__ __launch_bounds__(256) void k_gemm1m(
    const float* __restrict__ x, const uint4* __restrict__ w1f,
    float* __restrict__ h1) {
  const int t = threadIdx.x;
  const int lane = t & 63;
  const int wv = t >> 6;
  const int rb = blockIdx.x * 64 + wv * 16;
  int arow = rb + (lane & 15);
  if (arow >= N_NODES) arow = N_NODES - 1;   // clamp; stores predicated
  const float* aptr = x + (size_t)arow * F_IN + ((lane >> 4) << 3);

  f32x4 acc[4];
#pragma unroll
  for (int i = 0; i < 4; ++i) acc[i] = (f32x4){0.f, 0.f, 0.f, 0.f};

#pragma unroll 4
  for (int s = 0; s < 16; ++s) {
    float4 a0 = *reinterpret_cast<const float4*>(aptr + s * 32);
    float4 a1 = *reinterpret_cast<const float4*>(aptr + s * 32 + 4);
    uint4 b0 = w1f[(s * 4 + 0) * 64 + lane];
    uint4 b1 = w1f[(s * 4 + 1) * 64 + lane];
    uint4 b2 = w1f[(s * 4 + 2) * 64 + lane];
    uint4 b3 = w1f[(s * 4 + 3) * 64 + lane];
    bf16x8 af;
    af[0] = (__bf16)a0.x; af[1] = (__bf16)a0.y;
    af[2] = (__bf16)a0.z; af[3] = (__bf16)a0.w;
    af[4] = (__bf16)a1.x; af[5] = (__bf16)a1.y;
    af[6] = (__bf16)a1.z; af[7] = (__bf16)a1.w;
    acc[0] = __builtin_amdgcn_mfma_f32_16x16x32_bf16(af, __builtin_bit_cast(bf16x8, b0), acc[0], 0, 0, 0);
    acc[1] = __builtin_amdgcn_mfma_f32_16x16x32_bf16(af, __builtin_bit_cast(bf16x8, b1), acc[1], 0, 0, 0);
    acc[2] = __builtin_amdgcn_mfma_f32_16x16x32_bf16(af, __builtin_bit_cast(bf16x8, b2), acc[2], 0, 0, 0);
    acc[3] = __builtin_amdgcn_mfma_f32_16x16x32_bf16(af, __builtin_bit_cast(bf16x8, b3), acc[3], 0, 0, 0);
  }

  const int r0 = rb + ((lane >> 4) << 2);
  const int c = lane & 15;
#pragma unroll
  for (int tt = 0; tt < 4; ++tt) {
#pragma unroll
    for (int i = 0; i < 4; ++i) {
      int r = r0 + i;
      if (r < N_NODES) h1[(size_t)r * F_H + tt * 16 + c] = acc[tt][i];
    }
  }
}

// ---------------------------------------------------------------------------
// Per-node attention logits for layer 1: als/ald[n,head] = sum_f h1[n,head,f]*a
// Wave per node, lane = feature, 8-lane shfl reduce.
// ---------------------------------------------------------------------------
__global__ __launch_bounds__(256) void k_logits1(
    const float* __restrict__ h1, const float* __restrict__ a_src,
    const float* __restrict__ a_dst, float* __restrict__ als,
    float* __restrict__ ald) {
  int wid = (int)((blockIdx.x * 256 + threadIdx.x) >> 6);
  int lane = threadIdx.x & 63;
  if (wid >= N_NODES) return;
  float h = h1[(size_t)wid * F_H + lane];
  float s = h * a_src[lane];
  float d = h * a_dst[lane];
  s += __shfl_xor(s, 1); s += __shfl_xor(s, 2); s += __shfl_xor(s, 4);
  d += __shfl_xor(d, 1); d += __shfl_xor(d, 2); d += __shfl_xor(d, 4);
  if ((lane & 7) == 0) {
    als[(size_t)wid * HEADS + (lane >> 3)] = s;
    ald[(size_t)wid * HEADS + (lane >> 3)] = d;
  }
}

// ---------------------------------------------------------------------------
// Layer-1 edge softmax + aggregation + bias + ELU. Wave per node, lane=feature.
// Single pass (softmax shift-invariance; logits tiny), unrolled x4.
// ---------------------------------------------------------------------------
__global__ __launch_bounds__(256) void k_agg1(
    const int* __restrict__ rowstart, const int* __restrict__ csrc,
    const float* __restrict__ h1, const float* __restrict__ als,
    const float* __restrict__ ald, const float* __restrict__ b1,
    float* __restrict__ hact) {
  int wid = (int)((blockIdx.x * 256 + threadIdx.x) >> 6);
  int lane = threadIdx.x & 63;
  if (wid >= N_NODES) return;
  const int n = wid;
  const int e0 = rowstart[n], e1 = rowstart[n + 1];
  const int hh = lane >> 3;
  const float aldv = ald[(size_t)n * HEADS + hh];

  float denom = 0.f, acc = 0.f;
  int e = e0;
  for (; e + 4 <= e1; e += 4) {
    int s0 = csrc[e], s1 = csrc[e + 1], s2 = csrc[e + 2], s3 = csrc[e + 3];
    float a0 = als[(size_t)s0 * HEADS + hh];
    float a1 = als[(size_t)s1 * HEADS + hh];
    float a2 = als[(size_t)s2 * HEADS + hh];
    float a3 = als[(size_t)s3 * HEADS + hh];
    float f0 = h1[(size_t)s0 * F_H + lane];
    float f1 = h1[(size_t)s1 * F_H + lane];
    float f2 = h1[(size_t)s2 * F_H + lane];
    float f3 = h1[(size_t)s3 * F_H + lane];
    float v0 = a0 + aldv; v0 = (v0 > 0.f) ? v0 : NEG * v0;
    float v1 = a1 + aldv; v1 = (v1 > 0.f) ? v1 : NEG * v1;
    float v2 = a2 + aldv; v2 = (v2 > 0.f) ? v2 : NEG * v2;
    float v3 = a3 + aldv; v3 = (v3 > 0.f) ? v3 : NEG * v3;
    float p0 = __expf(v0), p1 = __expf(v1), p2 = __expf(v2), p3 = __expf(v3);
    denom += (p0 + p1) + (p2 + p3);
    acc += p0 * f0 + p1 * f1 + p2 * f2 + p3 * f3;
  }
  for (; e < e1; ++e) {
    int s = csrc[e];
    float v = als[(size_t)s * HEADS + hh] + aldv;
    v = (v > 0.f) ? v : NEG * v;
    float p = __expf(v);
    denom += p;
    acc += p * h1[(size_t)s * F_H + lane];
  }
  float o = acc / denom + b1[lane];
  o = (o > 0.f) ? o : expm1f(o);
  hact[(size_t)n * F_H + lane] = o;
}

// ---------------------------------------------------------------------------
// Layer-2 projection: h2 = hact @ W2 (64x40) + attention logits (1 head).
// ---------------------------------------------------------------------------
__global__ __launch_bounds__(256) void k_l2proj(
    const float* __restrict__ hact, const float* __restrict__ W2,
    const float* __restrict__ a_src2, const float* __restrict__ a_dst2,
    float* __restrict__ h2, float* __restrict__ als2, float* __restrict__ ald2) {
  __shared__ float hs[64 * 68];
  __shared__ float w2s[F_H * NC];
  const int t = threadIdx.x;
  const int nb = blockIdx.x * 64;
  {
    int r0 = t >> 4, c4 = t & 15;
#pragma unroll
    for (int i = 0; i < 4; ++i) {
      int r = r0 + i * 16;
      int gr = nb + r;
      float4 v = make_float4(0.f, 0.f, 0.f, 0.f);
      if (gr < N_NODES)
        v = *reinterpret_cast<const float4*>(&hact[(size_t)gr * F_H + c4 * 4]);
      *reinterpret_cast<float4*>(&hs[r * 68 + c4 * 4]) = v;
    }
  }
  for (int i = t; i < F_H * NC; i += 256) w2s[i] = W2[i];
  __syncthreads();

  const int node = t >> 2, cg = t & 3;
  float acc[10];
#pragma unroll
  for (int c = 0; c < 10; ++c) acc[c] = 0.f;
  for (int k = 0; k < F_H; ++k) {
    float xv = hs[node * 68 + k];
#pragma unroll
    for (int c = 0; c < 10; ++c) acc[c] += xv * w2s[k * NC + cg * 10 + c];
  }
  const int gn = nb + node;
  float ps = 0.f, pd = 0.f;
#pragma unroll
  for (int c = 0; c < 10; ++c) {
    ps += acc[c] * a_src2[cg * 10 + c];
    pd += acc[c] * a_dst2[cg * 10 + c];
  }
  ps += __shfl_xor(ps, 1); ps += __shfl_xor(ps, 2);
  pd += __shfl_xor(pd, 1); pd += __shfl_xor(pd, 2);
  if (gn < N_NODES) {
#pragma unroll
    for (int c = 0; c < 10; ++c) h2[(size_t)gn * NC + cg * 10 + c] = acc[c];
    if (cg == 0) { als2[gn] = ps; ald2[gn] = pd; }
  }
}

// ---------------------------------------------------------------------------
// Layer-2 edge softmax + aggregation + bias + log_softmax. Wave per node.
// ---------------------------------------------------------------------------
__global__ __launch_bounds__(256) void k_agg2(
    const int* __restrict__ rowstart, const int* __restrict__ csrc,
    const float* __restrict__ h2, const float* __restrict__ als2,
    const float* __restrict__ ald2, const float* __restrict__ b2,
    float* __restrict__ out) {
  int wid = (int)((blockIdx.x * 256 + threadIdx.x) >> 6);
  int lane = threadIdx.x & 63;
  if (wid >= N_NODES) return;
  const int n = wid;
  const int e0 = rowstart[n], e1 = rowstart[n + 1];
  const float aldv = ald2[n];
  const bool act = (lane < NC);
  const int fl = act ? lane : 0;

  float denom = 0.f, acc = 0.f;
  int e = e0;
  for (; e + 4 <= e1; e += 4) {
    int s0 = csrc[e], s1 = csrc[e + 1], s2 = csrc[e + 2], s3 = csrc[e + 3];
    float a0 = als2[s0], a1 = als2[s1], a2 = als2[s2], a3 = als2[s3];
    float f0 = h2[(size_t)s0 * NC + fl];
    float f1 = h2[(size_t)s1 * NC + fl];
    float f2 = h2[(size_t)s2 * NC + fl];
    float f3 = h2[(size_t)s3 * NC + fl];
    float v0 = a0 + aldv; v0 = (v0 > 0.f) ? v0 : NEG * v0;
    float v1 = a1 + aldv; v1 = (v1 > 0.f) ? v1 : NEG * v1;
    float v2 = a2 + aldv; v2 = (v2 > 0.f) ? v2 : NEG * v2;
    float v3 = a3 + aldv; v3 = (v3 > 0.f) ? v3 : NEG * v3;
    float p0 = __expf(v0), p1 = __expf(v1), p2 = __expf(v2), p3 = __expf(v3);
    denom += (p0 + p1) + (p2 + p3);
    acc += p0 * f0 + p1 * f1 + p2 * f2 + p3 * f3;
  }
  for (; e < e1; ++e) {
    int s = csrc[e];
    float v = als2[s] + aldv;
    v = (v > 0.f) ? v : NEG * v;
    float p = __expf(v);
    denom += p;
    acc += p * h2[(size_t)s * NC + fl];
  }
  float o = act ? (acc / denom + b2[lane]) : -1e30f;
  float mx = o;
#pragma unroll
  for (int d = 1; d < 64; d <<= 1) mx = fmaxf(mx, __shfl_xor(mx, d));
  float ex = act ? __expf(o - mx) : 0.f;
  float se = ex;
#pragma unroll
  for (int d = 1; d < 64; d <<= 1) se += __shfl_xor(se, d);
  if (act) out[(size_t)n * NC + lane] = (o - mx) - __logf(se);
}

// ---------------------------------------------------------------------------
extern "C" void kernel_launch(void* const* d_in, const int* in_sizes, int n_in,
                              void* d_out, int out_size, void* d_ws, size_t ws_size,
                              hipStream_t stream) {
  const float* x      = (const float*)d_in[0];
  const int*   ei     = (const int*)d_in[1];
  const float* W1     = (const float*)d_in[2];
  const float* a_src1 = (const float*)d_in[3];
  const float* a_dst1 = (const float*)d_in[4];
  const float* b1     = (const float*)d_in[5];
  const float* W2     = (const float*)d_in[6];
  const float* a_src2 = (const float*)d_in[7];
  const float* a_dst2 = (const float*)d_in[8];
  const float* b2     = (const float*)d_in[9];
  float* out = (float*)d_out;

  char* ws = (char*)d_ws;
  size_t o = 0;
  auto carve = [&](size_t bytes) -> char* {
    char* p = ws + o;
    o = (o + bytes + 255) & ~(size_t)255;
    return p;
  };
  int*   deg      = (int*)carve((size_t)N_NODES * 4);
  int*   part     = (int*)carve((size_t)N_NODES * 4);
  int*   bsum     = (int*)carve(2048);
  int*   rowstart = (int*)carve((size_t)(N_NODES + 1) * 4);
  int*   cursor   = (int*)carve((size_t)N_NODES * 4);
  int*   csrc     = (int*)carve((size_t)E_TOT * 4);
  int*   flag     = (int*)carve(256);
  uint4* w1f      = (uint4*)carve((size_t)4096 * 16);
  float* h1       = (float*)carve((size_t)N_NODES * F_H * 4);
  float* als1     = (float*)carve((size_t)N_NODES * HEADS * 4);
  float* ald1     = (float*)carve((size_t)N_NODES * HEADS * 4);
  float* hact     = (float*)carve((size_t)N_NODES * F_H * 4);
  float* h2       = (float*)carve((size_t)N_NODES * NC * 4);
  float* als2     = (float*)carve((size_t)N_NODES * 4);
  float* ald2     = (float*)carve((size_t)N_NODES * 4);
  (void)ws_size; (void)n_in; (void)in_sizes; (void)out_size;

  hipMemsetAsync(deg, 0, (size_t)N_NODES * 4, stream);
  k_detect<<<1, 64, 0, stream>>>(ei, flag);

  const int egrid = (E_TOT + 255) / 256;
  k_hist<<<egrid, 256, 0, stream>>>(ei, flag, deg);
  k_scanA<<<NBLK_SCAN, 256, 0, stream>>>(deg, part, bsum);
  k_scanB<<<1, 512, 0, stream>>>(bsum);
  k_scanC<<<NBLK_SCAN, 256, 0, stream>>>(part, bsum, rowstart, cursor);
  k_fill<<<egrid, 256, 0, stream>>>(ei, flag, cursor, csrc);

  k_packW<<<16, 256, 0, stream>>>(W1, w1f);
  k_gemm1m<<<(N_NODES + 63) / 64, 256, 0, stream>>>(x, w1f, h1);
  k_logits1<<<(N_NODES * 64 + 255) / 256, 256, 0, stream>>>(h1, a_src1, a_dst1, als1, ald1);
  k_agg1<<<(N_NODES * 64 + 255) / 256, 256, 0, stream>>>(rowstart, csrc, h1, als1, ald1, b1, hact);
  k_l2proj<<<(N_NODES + 63) / 64, 256, 0, stream>>>(hact, W2, a_src2, a_dst2, h2, als2, ald2);
  k_agg2<<<(N_NODES * 64 + 255) / 256, 256, 0, stream>>>(rowstart, csrc, h2, als2, ald2, b2, out);
}

// Round 4
// 365.271 us; speedup vs baseline: 2.4956x; 1.3342x over previous
//
#include <hip/hip_runtime.h>
#include <hip/hip_bf16.h>
#include <cstdint>
#include <cstddef>

#define N_NODES 100000
#define N_EDGES 1600000
#define E_TOT   (N_EDGES + N_NODES)
#define F_IN    512
#define HEADS   8
#define HID     8
#define F_H     64          // HEADS*HID
#define NC      40
#define NEG     0.2f

#define BSH    8            // bucket = dst >> 8 (256 nodes/bucket)
#define NB     391          // ceil(100000/256)
#define CHUNK  8192         // edges per k_bhist/k_bfill block
#define NBLK_E ((E_TOT + CHUNK - 1) / CHUNK)   // 208
#define CAP    7168         // k_cfill LDS staging entries (avg seg ~4350)

typedef __attribute__((ext_vector_type(8))) __bf16 bf16x8;
typedef __attribute__((ext_vector_type(4))) float f32x4;
typedef __attribute__((ext_vector_type(8))) unsigned short u16x8;

// ---------------------------------------------------------------------------
// edge_index dtype probe: int64 -> every odd int32 word of first entries is 0.
// ---------------------------------------------------------------------------
__global__ void k_detect(const int* __restrict__ ei, int* __restrict__ flag) {
  if (threadIdx.x == 0 && blockIdx.x == 0) {
    int nz = 0;
    for (int i = 0; i < 256; ++i) nz |= ei[2 * i + 1];
    *flag = (nz == 0) ? 1 : 0;
  }
}

__device__ __forceinline__ int load_dst(const int* __restrict__ ei, bool f, int i) {
  if (i < N_EDGES) return f ? ei[2 * (N_EDGES + i)] : ei[N_EDGES + i];
  return i - N_EDGES;
}
__device__ __forceinline__ int load_src(const int* __restrict__ ei, bool f, int i) {
  if (i < N_EDGES) return f ? ei[2 * i] : ei[i];
  return i - N_EDGES;
}

// ---------------------------------------------------------------------------
// Bucket histogram (LDS-binned, one global atomic per block-bucket).
// ---------------------------------------------------------------------------
__global__ __launch_bounds__(256) void k_bhist(const int* __restrict__ ei,
                                               const int* __restrict__ flag,
                                               int* __restrict__ bcnt) {
  __shared__ int h[NB];
  const int t = threadIdx.x;
  for (int i = t; i < NB; i += 256) h[i] = 0;
  __syncthreads();
  const bool f = (*flag) != 0;
  const int base = blockIdx.x * CHUNK;
#pragma unroll
  for (int j = 0; j < CHUNK / 256; ++j) {
    int i = base + t + j * 256;
    if (i < E_TOT) atomicAdd(&h[load_dst(ei, f, i) >> BSH], 1);
  }
  __syncthreads();
  for (int i = t; i < NB; i += 256)
    if (h[i]) atomicAdd(&bcnt[i], h[i]);
}

// ---------------------------------------------------------------------------
// Bucket exclusive scan (391 values, one block). Also seeds bcur and tails.
// ---------------------------------------------------------------------------
__global__ __launch_bounds__(512) void k_bscan(const int* __restrict__ bcnt,
                                               int* __restrict__ bstart,
                                               int* __restrict__ bcur,
                                               int* __restrict__ rowstart) {
  __shared__ int sh[512];
  const int t = threadIdx.x;
  int v = (t < NB) ? bcnt[t] : 0;
  sh[t] = v;
  __syncthreads();
  for (int d = 1; d < 512; d <<= 1) {
    int u = (t >= d) ? sh[t - d] : 0;
    __syncthreads();
    sh[t] += u;
    __syncthreads();
  }
  if (t < NB) {
    int e = sh[t] - v;
    bstart[t] = e;
    bcur[t] = e;
  }
  if (t == 0) { bstart[NB] = E_TOT; rowstart[N_NODES] = E_TOT; }
}

// ---------------------------------------------------------------------------
// Pass 1: bin CHUNK edges in LDS by bucket, flush contiguous per-bucket runs
// to the intermediate array at atomically-reserved offsets. Entry packing:
// (dst&255)<<24 | src  (src < 2^17 fits).
// ---------------------------------------------------------------------------
__global__ __launch_bounds__(256) void k_bfill(const int* __restrict__ ei,
                                               const int* __restrict__ flag,
                                               int* __restrict__ bcur,
                                               unsigned int* __restrict__ inter) {
  __shared__ unsigned int ent[CHUNK];                 // 32 KB
  __shared__ int h[NB], ofs[NB], cur[NB], gpos[NB];   // ~6.3 KB
  const int t = threadIdx.x;
  const int base = blockIdx.x * CHUNK;
  const bool f = (*flag) != 0;
  for (int i = t; i < NB; i += 256) h[i] = 0;
  __syncthreads();
#pragma unroll
  for (int j = 0; j < CHUNK / 256; ++j) {
    int i = base + t + j * 256;
    if (i < E_TOT) atomicAdd(&h[load_dst(ei, f, i) >> BSH], 1);
  }
  __syncthreads();
  // exclusive scan h -> ofs: wave 0, 7 buckets per lane + shfl_up lane scan
  if (t < 64) {
    int loc[7];
    int s = 0;
#pragma unroll
    for (int k = 0; k < 7; ++k) {
      int idx = t * 7 + k;
      int hv = (idx < NB) ? h[idx] : 0;
      loc[k] = s;
      s += hv;
    }
    int incl = s;
    for (int dd = 1; dd < 64; dd <<= 1) {
      int u = __shfl_up(incl, dd);
      if (t >= dd) incl += u;
    }
    int excl = incl - s;
#pragma unroll
    for (int k = 0; k < 7; ++k) {
      int idx = t * 7 + k;
      if (idx < NB) ofs[idx] = excl + loc[k];
    }
  }
  __syncthreads();
  for (int i = t; i < NB; i += 256) {
    cur[i] = ofs[i];
    gpos[i] = h[i] ? atomicAdd(&bcur[i], h[i]) : 0;
  }
  __syncthreads();
#pragma unroll
  for (int j = 0; j < CHUNK / 256; ++j) {
    int i = base + t + j * 256;
    if (i < E_TOT) {
      int s = load_src(ei, f, i);
      int d = load_dst(ei, f, i);
      int p = atomicAdd(&cur[d >> BSH], 1);
      ent[p] = ((unsigned int)(d & 255) << 24) | (unsigned int)s;
    }
  }
  __syncthreads();
  const int wv = t >> 6, ln = t & 63;
  for (int b = wv; b < NB; b += 4) {
    int c = h[b];
    if (!c) continue;
    int g = gpos[b], o = ofs[b];
    for (int i = ln; i < c; i += 64) inter[g + i] = ent[o + i];
  }
}

// ---------------------------------------------------------------------------
// Pass 2: one block per bucket. Counting sort of the bucket's entries into
// the final csrc segment, entirely in LDS; writes csrc + rowstart coalesced.
// ---------------------------------------------------------------------------
__global__ __launch_bounds__(256) void k_cfill(const unsigned int* __restrict__ inter,
                                               const int* __restrict__ bstart,
                                               int* __restrict__ rowstart,
                                               int* __restrict__ csrc) {
  __shared__ unsigned int out_l[CAP];      // 28 KB
  __shared__ int cnt[256], sc[256], cur2[256];
  const int t = threadIdx.x;
  const int b = blockIdx.x;
  const int segStart = bstart[b];
  const int L = bstart[b + 1] - segStart;
  cnt[t] = 0;
  __syncthreads();
  for (int i = t; i < L; i += 256) atomicAdd(&cnt[inter[segStart + i] >> 24], 1);
  __syncthreads();
  sc[t] = cnt[t];
  __syncthreads();
  for (int d = 1; d < 256; d <<= 1) {
    int v = (t >= d) ? sc[t - d] : 0;
    __syncthreads();
    sc[t] += v;
    __syncthreads();
  }
  const int excl = sc[t] - cnt[t];
  cur2[t] = excl;
  const int node = (b << BSH) + t;
  if (node < N_NODES) rowstart[node] = segStart + excl;
  __syncthreads();
  if (L <= CAP) {
    for (int i = t; i < L; i += 256) {
      unsigned int e = inter[segStart + i];
      int p = atomicAdd(&cur2[e >> 24], 1);
      out_l[p] = e & 0xFFFFFFu;
    }
    __syncthreads();
    for (int i = t; i < L; i += 256) csrc[segStart + i] = (int)out_l[i];
  } else {  // safety fallback (statistically never taken)
    for (int i = t; i < L; i += 256) {
      unsigned int e = inter[segStart + i];
      int p = atomicAdd(&cur2[e >> 24], 1);
      csrc[segStart + p] = (int)(e & 0xFFFFFFu);
    }
  }
}

// ---------------------------------------------------------------------------
// W1 repack: fp32 (512x64) -> bf16 B-fragment-major for mfma_f32_16x16x32_bf16.
// ---------------------------------------------------------------------------
__global__ __launch_bounds__(256) void k_packW(const float* __restrict__ W1,
                                               uint4* __restrict__ w1f) {
  int tid = blockIdx.x * 256 + threadIdx.x;   // 0..4095
  if (tid >= 4096) return;
  int lane = tid & 63;
  int t = (tid >> 6) & 3;
  int s = tid >> 8;
  int k0 = s * 32 + ((lane >> 4) << 3);
  int col = t * 16 + (lane & 15);
  u16x8 v;
#pragma unroll
  for (int i = 0; i < 8; ++i) {
    __hip_bfloat16 b = __float2bfloat16(W1[(size_t)(k0 + i) * F_H + col]);
    v[i] = __builtin_bit_cast(unsigned short, b);
  }
  w1f[tid] = __builtin_bit_cast(uint4, v);
}

// ---------------------------------------------------------------------------
// GEMM1 via MFMA + fused per-head attention logits.
// Wave owns 16 rows x 64 cols; no LDS, no barriers.
// D frag: col = lane&15, row = (lane>>4)*4+reg.
// Logits: head of col = tt*2 + (c>>3); reduce over 8 lanes (xor 1,2,4).
// ---------------------------------------------------------------------------
__global__ __launch_bounds__(256) void k_gemm1m(
    const float* __restrict__ x, const uint4* __restrict__ w1f,
    const float* __restrict__ a_src, const float* __restrict__ a_dst,
    float* __restrict__ h1, float* __restrict__ als, float* __restrict__ ald) {
  const int t = threadIdx.x;
  const int lane = t & 63;
  const int wv = t >> 6;
  const int rb = blockIdx.x * 64 + wv * 16;
  int arow = rb + (lane & 15);
  if (arow >= N_NODES) arow = N_NODES - 1;   // clamp; stores predicated
  const float* aptr = x + (size_t)arow * F_IN + ((lane >> 4) << 3);

  f32x4 acc[4];
#pragma unroll
  for (int i = 0; i < 4; ++i) acc[i] = (f32x4){0.f, 0.f, 0.f, 0.f};

#pragma unroll 4
  for (int s = 0; s < 16; ++s) {
    float4 a0 = *reinterpret_cast<const float4*>(aptr + s * 32);
    float4 a1 = *reinterpret_cast<const float4*>(aptr + s * 32 + 4);
    uint4 b0 = w1f[(s * 4 + 0) * 64 + lane];
    uint4 b1 = w1f[(s * 4 + 1) * 64 + lane];
    uint4 b2 = w1f[(s * 4 + 2) * 64 + lane];
    uint4 b3 = w1f[(s * 4 + 3) * 64 + lane];
    bf16x8 af;
    af[0] = (__bf16)a0.x; af[1] = (__bf16)a0.y;
    af[2] = (__bf16)a0.z; af[3] = (__bf16)a0.w;
    af[4] = (__bf16)a1.x; af[5] = (__bf16)a1.y;
    af[6] = (__bf16)a1.z; af[7] = (__bf16)a1.w;
    acc[0] = __builtin_amdgcn_mfma_f32_16x16x32_bf16(af, __builtin_bit_cast(bf16x8, b0), acc[0], 0, 0, 0);
    acc[1] = __builtin_amdgcn_mfma_f32_16x16x32_bf16(af, __builtin_bit_cast(bf16x8, b1), acc[1], 0, 0, 0);
    acc[2] = __builtin_amdgcn_mfma_f32_16x16x32_bf16(af, __builtin_bit_cast(bf16x8, b2), acc[2], 0, 0, 0);
    acc[3] = __builtin_amdgcn_mfma_f32_16x16x32_bf16(af, __builtin_bit_cast(bf16x8, b3), acc[3], 0, 0, 0);
  }

  const int r0 = rb + ((lane >> 4) << 2);
  const int c = lane & 15;
#pragma unroll
  for (int tt = 0; tt < 4; ++tt) {
#pragma unroll
    for (int i = 0; i < 4; ++i) {
      int r = r0 + i;
      if (r < N_NODES) h1[(size_t)r * F_H + tt * 16 + c] = acc[tt][i];
    }
  }

  // fused logits
  float asw[4], adw[4];
#pragma unroll
  for (int tt = 0; tt < 4; ++tt) {
    asw[tt] = a_src[tt * 16 + c];
    adw[tt] = a_dst[tt * 16 + c];
  }
  float sp[4][4], dp[4][4];
#pragma unroll
  for (int tt = 0; tt < 4; ++tt)
#pragma unroll
    for (int i = 0; i < 4; ++i) {
      sp[tt][i] = acc[tt][i] * asw[tt];
      dp[tt][i] = acc[tt][i] * adw[tt];
    }
#pragma unroll
  for (int dd = 1; dd < 8; dd <<= 1)
#pragma unroll
    for (int tt = 0; tt < 4; ++tt)
#pragma unroll
      for (int i = 0; i < 4; ++i) {
        sp[tt][i] += __shfl_xor(sp[tt][i], dd);
        dp[tt][i] += __shfl_xor(dp[tt][i], dd);
      }
  if ((c & 7) == 0) {
    const int hb = c >> 3;
#pragma unroll
    for (int i = 0; i < 4; ++i) {
      int r = r0 + i;
      if (r < N_NODES) {
#pragma unroll
        for (int tt = 0; tt < 4; ++tt) {
          als[(size_t)r * HEADS + tt * 2 + hb] = sp[tt][i];
          ald[(size_t)r * HEADS + tt * 2 + hb] = dp[tt][i];
        }
      }
    }
  }
}

// ---------------------------------------------------------------------------
// Layer-1 edge softmax + aggregation + bias + ELU. Wave per node, lane=feature.
// Single pass (softmax shift-invariance; logits tiny), unrolled x4.
// ---------------------------------------------------------------------------
__global__ __launch_bounds__(256) void k_agg1(
    const int* __restrict__ rowstart, const int* __restrict__ csrc,
    const float* __restrict__ h1, const float* __restrict__ als,
    const float* __restrict__ ald, const float* __restrict__ b1,
    float* __restrict__ hact) {
  int wid = (int)((blockIdx.x * 256 + threadIdx.x) >> 6);
  int lane = threadIdx.x & 63;
  if (wid >= N_NODES) return;
  const int n = wid;
  const int e0 = rowstart[n], e1 = rowstart[n + 1];
  const int hh = lane >> 3;
  const float aldv = ald[(size_t)n * HEADS + hh];

  float denom = 0.f, acc = 0.f;
  int e = e0;
  for (; e + 4 <= e1; e += 4) {
    int s0 = csrc[e], s1 = csrc[e + 1], s2 = csrc[e + 2], s3 = csrc[e + 3];
    float a0 = als[(size_t)s0 * HEADS + hh];
    float a1 = als[(size_t)s1 * HEADS + hh];
    float a2 = als[(size_t)s2 * HEADS + hh];
    float a3 = als[(size_t)s3 * HEADS + hh];
    float f0 = h1[(size_t)s0 * F_H + lane];
    float f1 = h1[(size_t)s1 * F_H + lane];
    float f2 = h1[(size_t)s2 * F_H + lane];
    float f3 = h1[(size_t)s3 * F_H + lane];
    float v0 = a0 + aldv; v0 = (v0 > 0.f) ? v0 : NEG * v0;
    float v1 = a1 + aldv; v1 = (v1 > 0.f) ? v1 : NEG * v1;
    float v2 = a2 + aldv; v2 = (v2 > 0.f) ? v2 : NEG * v2;
    float v3 = a3 + aldv; v3 = (v3 > 0.f) ? v3 : NEG * v3;
    float p0 = __expf(v0), p1 = __expf(v1), p2 = __expf(v2), p3 = __expf(v3);
    denom += (p0 + p1) + (p2 + p3);
    acc += p0 * f0 + p1 * f1 + p2 * f2 + p3 * f3;
  }
  for (; e < e1; ++e) {
    int s = csrc[e];
    float v = als[(size_t)s * HEADS + hh] + aldv;
    v = (v > 0.f) ? v : NEG * v;
    float p = __expf(v);
    denom += p;
    acc += p * h1[(size_t)s * F_H + lane];
  }
  float o = acc / denom + b1[lane];
  o = (o > 0.f) ? o : expm1f(o);
  hact[(size_t)n * F_H + lane] = o;
}

// ---------------------------------------------------------------------------
// Layer-2 projection: h2 = hact @ W2 (64x40) + attention logits (1 head).
// ---------------------------------------------------------------------------
__global__ __launch_bounds__(256) void k_l2proj(
    const float* __restrict__ hact, const float* __restrict__ W2,
    const float* __restrict__ a_src2, const float* __restrict__ a_dst2,
    float* __restrict__ h2, float* __restrict__ als2, float* __restrict__ ald2) {
  __shared__ float hs[64 * 68];
  __shared__ float w2s[F_H * NC];
  const int t = threadIdx.x;
  const int nb = blockIdx.x * 64;
  {
    int r0 = t >> 4, c4 = t & 15;
#pragma unroll
    for (int i = 0; i < 4; ++i) {
      int r = r0 + i * 16;
      int gr = nb + r;
      float4 v = make_float4(0.f, 0.f, 0.f, 0.f);
      if (gr < N_NODES)
        v = *reinterpret_cast<const float4*>(&hact[(size_t)gr * F_H + c4 * 4]);
      *reinterpret_cast<float4*>(&hs[r * 68 + c4 * 4]) = v;
    }
  }
  for (int i = t; i < F_H * NC; i += 256) w2s[i] = W2[i];
  __syncthreads();

  const int node = t >> 2, cg = t & 3;
  float acc[10];
#pragma unroll
  for (int c = 0; c < 10; ++c) acc[c] = 0.f;
  for (int k = 0; k < F_H; ++k) {
    float xv = hs[node * 68 + k];
#pragma unroll
    for (int c = 0; c < 10; ++c) acc[c] += xv * w2s[k * NC + cg * 10 + c];
  }
  const int gn = nb + node;
  float ps = 0.f, pd = 0.f;
#pragma unroll
  for (int c = 0; c < 10; ++c) {
    ps += acc[c] * a_src2[cg * 10 + c];
    pd += acc[c] * a_dst2[cg * 10 + c];
  }
  ps += __shfl_xor(ps, 1); ps += __shfl_xor(ps, 2);
  pd += __shfl_xor(pd, 1); pd += __shfl_xor(pd, 2);
  if (gn < N_NODES) {
#pragma unroll
    for (int c = 0; c < 10; ++c) h2[(size_t)gn * NC + cg * 10 + c] = acc[c];
    if (cg == 0) { als2[gn] = ps; ald2[gn] = pd; }
  }
}

// ---------------------------------------------------------------------------
// Layer-2 edge softmax + aggregation + bias + log_softmax. Wave per node.
// ---------------------------------------------------------------------------
__global__ __launch_bounds__(256) void k_agg2(
    const int* __restrict__ rowstart, const int* __restrict__ csrc,
    const float* __restrict__ h2, const float* __restrict__ als2,
    const float* __restrict__ ald2, const float* __restrict__ b2,
    float* __restrict__ out) {
  int wid = (int)((blockIdx.x * 256 + threadIdx.x) >> 6);
  int lane = threadIdx.x & 63;
  if (wid >= N_NODES) return;
  const int n = wid;
  const int e0 = rowstart[n], e1 = rowstart[n + 1];
  const float aldv = ald2[n];
  const bool act = (lane < NC);
  const int fl = act ? lane : 0;

  float denom = 0.f, acc = 0.f;
  int e = e0;
  for (; e + 4 <= e1; e += 4) {
    int s0 = csrc[e], s1 = csrc[e + 1], s2 = csrc[e + 2], s3 = csrc[e + 3];
    float a0 = als2[s0], a1 = als2[s1], a2 = als2[s2], a3 = als2[s3];
    float f0 = h2[(size_t)s0 * NC + fl];
    float f1 = h2[(size_t)s1 * NC + fl];
    float f2 = h2[(size_t)s2 * NC + fl];
    float f3 = h2[(size_t)s3 * NC + fl];
    float v0 = a0 + aldv; v0 = (v0 > 0.f) ? v0 : NEG * v0;
    float v1 = a1 + aldv; v1 = (v1 > 0.f) ? v1 : NEG * v1;
    float v2 = a2 + aldv; v2 = (v2 > 0.f) ? v2 : NEG * v2;
    float v3 = a3 + aldv; v3 = (v3 > 0.f) ? v3 : NEG * v3;
    float p0 = __expf(v0), p1 = __expf(v1), p2 = __expf(v2), p3 = __expf(v3);
    denom += (p0 + p1) + (p2 + p3);
    acc += p0 * f0 + p1 * f1 + p2 * f2 + p3 * f3;
  }
  for (; e < e1; ++e) {
    int s = csrc[e];
    float v = als2[s] + aldv;
    v = (v > 0.f) ? v : NEG * v;
    float p = __expf(v);
    denom += p;
    acc += p * h2[(size_t)s * NC + fl];
  }
  float o = act ? (acc / denom + b2[lane]) : -1e30f;
  float mx = o;
#pragma unroll
  for (int d = 1; d < 64; d <<= 1) mx = fmaxf(mx, __shfl_xor(mx, d));
  float ex = act ? __expf(o - mx) : 0.f;
  float se = ex;
#pragma unroll
  for (int d = 1; d < 64; d <<= 1) se += __shfl_xor(se, d);
  if (act) out[(size_t)n * NC + lane] = (o - mx) - __logf(se);
}

// ---------------------------------------------------------------------------
extern "C" void kernel_launch(void* const* d_in, const int* in_sizes, int n_in,
                              void* d_out, int out_size, void* d_ws, size_t ws_size,
                              hipStream_t stream) {
  const float* x      = (const float*)d_in[0];
  const int*   ei     = (const int*)d_in[1];
  const float* W1     = (const float*)d_in[2];
  const float* a_src1 = (const float*)d_in[3];
  const float* a_dst1 = (const float*)d_in[4];
  const float* b1     = (const float*)d_in[5];
  const float* W2     = (const float*)d_in[6];
  const float* a_src2 = (const float*)d_in[7];
  const float* a_dst2 = (const float*)d_in[8];
  const float* b2     = (const float*)d_in[9];
  float* out = (float*)d_out;

  char* ws = (char*)d_ws;
  size_t o = 0;
  auto carve = [&](size_t bytes) -> char* {
    char* p = ws + o;
    o = (o + bytes + 255) & ~(size_t)255;
    return p;
  };
  int*   flag     = (int*)carve(256);
  int*   bcnt     = (int*)carve((size_t)NB * 4);
  int*   bstart   = (int*)carve((size_t)(NB + 1) * 4);
  int*   bcur     = (int*)carve((size_t)NB * 4);
  int*   rowstart = (int*)carve((size_t)(N_NODES + 1) * 4);
  unsigned int* inter = (unsigned int*)carve((size_t)E_TOT * 4);
  int*   csrc     = (int*)carve((size_t)E_TOT * 4);
  uint4* w1f      = (uint4*)carve((size_t)4096 * 16);
  float* h1       = (float*)carve((size_t)N_NODES * F_H * 4);
  float* als1     = (float*)carve((size_t)N_NODES * HEADS * 4);
  float* ald1     = (float*)carve((size_t)N_NODES * HEADS * 4);
  float* hact     = (float*)carve((size_t)N_NODES * F_H * 4);
  float* h2       = (float*)carve((size_t)N_NODES * NC * 4);
  float* als2     = (float*)carve((size_t)N_NODES * 4);
  float* ald2     = (float*)carve((size_t)N_NODES * 4);
  (void)ws_size; (void)n_in; (void)in_sizes; (void)out_size;

  hipMemsetAsync(bcnt, 0, (size_t)NB * 4, stream);
  k_detect<<<1, 64, 0, stream>>>(ei, flag);
  k_bhist<<<NBLK_E, 256, 0, stream>>>(ei, flag, bcnt);
  k_bscan<<<1, 512, 0, stream>>>(bcnt, bstart, bcur, rowstart);
  k_bfill<<<NBLK_E, 256, 0, stream>>>(ei, flag, bcur, inter);
  k_cfill<<<NB, 256, 0, stream>>>(inter, bstart, rowstart, csrc);

  k_packW<<<16, 256, 0, stream>>>(W1, w1f);
  k_gemm1m<<<(N_NODES + 63) / 64, 256, 0, stream>>>(x, w1f, a_src1, a_dst1, h1, als1, ald1);
  k_agg1<<<(N_NODES * 64 + 255) / 256, 256, 0, stream>>>(rowstart, csrc, h1, als1, ald1, b1, hact);
  k_l2proj<<<(N_NODES + 63) / 64, 256, 0, stream>>>(hact, W2, a_src2, a_dst2, h2, als2, ald2);
  k_agg2<<<(N_NODES * 64 + 255) / 256, 256, 0, stream>>>(rowstart, csrc, h2, als2, ald2, b2, out);
}

// Round 5
// 348.254 us; speedup vs baseline: 2.6175x; 1.0489x over previous
//
#include <hip/hip_runtime.h>
#include <hip/hip_bf16.h>
#include <cstdint>
#include <cstddef>

#define N_NODES 100000
#define N_EDGES 1600000
#define E_TOT   (N_EDGES + N_NODES)
#define F_IN    512
#define HEADS   8
#define HID     8
#define F_H     64          // HEADS*HID
#define NC      40
#define NEG     0.2f

#define BSH    8            // bucket = dst >> 8 (256 nodes/bucket)
#define NB     391          // ceil(100000/256)
#define CHUNK  8192         // edges per k_bhist/k_bfill block
#define NBLK_E ((E_TOT + CHUNK - 1) / CHUNK)   // 208
#define CAP    7168         // k_cfill LDS staging entries (avg seg ~4350)

typedef __attribute__((ext_vector_type(8))) __bf16 bf16x8;
typedef __attribute__((ext_vector_type(4))) float f32x4;
typedef __attribute__((ext_vector_type(8))) unsigned short u16x8;

__device__ __forceinline__ float bf2f(unsigned short u) {
  unsigned int w = ((unsigned int)u) << 16;
  return __builtin_bit_cast(float, w);
}
__device__ __forceinline__ unsigned short f2bf(float f) {
  __hip_bfloat16 b = __float2bfloat16(f);
  return __builtin_bit_cast(unsigned short, b);
}

// ---------------------------------------------------------------------------
// edge_index dtype probe: int64 -> every odd int32 word of first entries is 0.
// ---------------------------------------------------------------------------
__global__ void k_detect(const int* __restrict__ ei, int* __restrict__ flag) {
  if (threadIdx.x == 0 && blockIdx.x == 0) {
    int nz = 0;
    for (int i = 0; i < 256; ++i) nz |= ei[2 * i + 1];
    *flag = (nz == 0) ? 1 : 0;
  }
}

__device__ __forceinline__ int load_dst(const int* __restrict__ ei, bool f, int i) {
  if (i < N_EDGES) return f ? ei[2 * (N_EDGES + i)] : ei[N_EDGES + i];
  return i - N_EDGES;
}
__device__ __forceinline__ int load_src(const int* __restrict__ ei, bool f, int i) {
  if (i < N_EDGES) return f ? ei[2 * i] : ei[i];
  return i - N_EDGES;
}

// ---------------------------------------------------------------------------
// Bucket histogram (LDS-binned, one global atomic per block-bucket).
// ---------------------------------------------------------------------------
__global__ __launch_bounds__(256) void k_bhist(const int* __restrict__ ei,
                                               const int* __restrict__ flag,
                                               int* __restrict__ bcnt) {
  __shared__ int h[NB];
  const int t = threadIdx.x;
  for (int i = t; i < NB; i += 256) h[i] = 0;
  __syncthreads();
  const bool f = (*flag) != 0;
  const int base = blockIdx.x * CHUNK;
#pragma unroll
  for (int j = 0; j < CHUNK / 256; ++j) {
    int i = base + t + j * 256;
    if (i < E_TOT) atomicAdd(&h[load_dst(ei, f, i) >> BSH], 1);
  }
  __syncthreads();
  for (int i = t; i < NB; i += 256)
    if (h[i]) atomicAdd(&bcnt[i], h[i]);
}

// ---------------------------------------------------------------------------
// Bucket exclusive scan (391 values, one block). Also seeds bcur and tails.
// ---------------------------------------------------------------------------
__global__ __launch_bounds__(512) void k_bscan(const int* __restrict__ bcnt,
                                               int* __restrict__ bstart,
                                               int* __restrict__ bcur,
                                               int* __restrict__ rowstart) {
  __shared__ int sh[512];
  const int t = threadIdx.x;
  int v = (t < NB) ? bcnt[t] : 0;
  sh[t] = v;
  __syncthreads();
  for (int d = 1; d < 512; d <<= 1) {
    int u = (t >= d) ? sh[t - d] : 0;
    __syncthreads();
    sh[t] += u;
    __syncthreads();
  }
  if (t < NB) {
    int e = sh[t] - v;
    bstart[t] = e;
    bcur[t] = e;
  }
  if (t == 0) { bstart[NB] = E_TOT; rowstart[N_NODES] = E_TOT; }
}

// ---------------------------------------------------------------------------
// Pass 1: bin CHUNK edges in LDS by bucket, flush contiguous per-bucket runs.
// Entry packing: (dst&255)<<24 | src.
// ---------------------------------------------------------------------------
__global__ __launch_bounds__(256) void k_bfill(const int* __restrict__ ei,
                                               const int* __restrict__ flag,
                                               int* __restrict__ bcur,
                                               unsigned int* __restrict__ inter) {
  __shared__ unsigned int ent[CHUNK];                 // 32 KB
  __shared__ int h[NB], ofs[NB], cur[NB], gpos[NB];   // ~6.3 KB
  const int t = threadIdx.x;
  const int base = blockIdx.x * CHUNK;
  const bool f = (*flag) != 0;
  for (int i = t; i < NB; i += 256) h[i] = 0;
  __syncthreads();
#pragma unroll
  for (int j = 0; j < CHUNK / 256; ++j) {
    int i = base + t + j * 256;
    if (i < E_TOT) atomicAdd(&h[load_dst(ei, f, i) >> BSH], 1);
  }
  __syncthreads();
  if (t < 64) {
    int loc[7];
    int s = 0;
#pragma unroll
    for (int k = 0; k < 7; ++k) {
      int idx = t * 7 + k;
      int hv = (idx < NB) ? h[idx] : 0;
      loc[k] = s;
      s += hv;
    }
    int incl = s;
    for (int dd = 1; dd < 64; dd <<= 1) {
      int u = __shfl_up(incl, dd);
      if (t >= dd) incl += u;
    }
    int excl = incl - s;
#pragma unroll
    for (int k = 0; k < 7; ++k) {
      int idx = t * 7 + k;
      if (idx < NB) ofs[idx] = excl + loc[k];
    }
  }
  __syncthreads();
  for (int i = t; i < NB; i += 256) {
    cur[i] = ofs[i];
    gpos[i] = h[i] ? atomicAdd(&bcur[i], h[i]) : 0;
  }
  __syncthreads();
#pragma unroll
  for (int j = 0; j < CHUNK / 256; ++j) {
    int i = base + t + j * 256;
    if (i < E_TOT) {
      int s = load_src(ei, f, i);
      int d = load_dst(ei, f, i);
      int p = atomicAdd(&cur[d >> BSH], 1);
      ent[p] = ((unsigned int)(d & 255) << 24) | (unsigned int)s;
    }
  }
  __syncthreads();
  const int wv = t >> 6, ln = t & 63;
  for (int b = wv; b < NB; b += 4) {
    int c = h[b];
    if (!c) continue;
    int g = gpos[b], o = ofs[b];
    for (int i = ln; i < c; i += 64) inter[g + i] = ent[o + i];
  }
}

// ---------------------------------------------------------------------------
// Pass 2: one block per bucket; LDS counting sort -> csrc + rowstart coalesced.
// ---------------------------------------------------------------------------
__global__ __launch_bounds__(256) void k_cfill(const unsigned int* __restrict__ inter,
                                               const int* __restrict__ bstart,
                                               int* __restrict__ rowstart,
                                               int* __restrict__ csrc) {
  __shared__ unsigned int out_l[CAP];      // 28 KB
  __shared__ int cnt[256], sc[256], cur2[256];
  const int t = threadIdx.x;
  const int b = blockIdx.x;
  const int segStart = bstart[b];
  const int L = bstart[b + 1] - segStart;
  cnt[t] = 0;
  __syncthreads();
  for (int i = t; i < L; i += 256) atomicAdd(&cnt[inter[segStart + i] >> 24], 1);
  __syncthreads();
  sc[t] = cnt[t];
  __syncthreads();
  for (int d = 1; d < 256; d <<= 1) {
    int v = (t >= d) ? sc[t - d] : 0;
    __syncthreads();
    sc[t] += v;
    __syncthreads();
  }
  const int excl = sc[t] - cnt[t];
  cur2[t] = excl;
  const int node = (b << BSH) + t;
  if (node < N_NODES) rowstart[node] = segStart + excl;
  __syncthreads();
  if (L <= CAP) {
    for (int i = t; i < L; i += 256) {
      unsigned int e = inter[segStart + i];
      int p = atomicAdd(&cur2[e >> 24], 1);
      out_l[p] = e & 0xFFFFFFu;
    }
    __syncthreads();
    for (int i = t; i < L; i += 256) csrc[segStart + i] = (int)out_l[i];
  } else {  // safety fallback (statistically never taken)
    for (int i = t; i < L; i += 256) {
      unsigned int e = inter[segStart + i];
      int p = atomicAdd(&cur2[e >> 24], 1);
      csrc[segStart + p] = (int)(e & 0xFFFFFFu);
    }
  }
}

// ---------------------------------------------------------------------------
// W1 repack: fp32 (512x64) -> bf16 B-fragment-major for mfma_f32_16x16x32_bf16.
// ---------------------------------------------------------------------------
__global__ __launch_bounds__(256) void k_packW(const float* __restrict__ W1,
                                               uint4* __restrict__ w1f) {
  int tid = blockIdx.x * 256 + threadIdx.x;   // 0..4095
  if (tid >= 4096) return;
  int lane = tid & 63;
  int t = (tid >> 6) & 3;
  int s = tid >> 8;
  int k0 = s * 32 + ((lane >> 4) << 3);
  int col = t * 16 + (lane & 15);
  u16x8 v;
#pragma unroll
  for (int i = 0; i < 8; ++i) v[i] = f2bf(W1[(size_t)(k0 + i) * F_H + col]);
  w1f[tid] = __builtin_bit_cast(uint4, v);
}

// ---------------------------------------------------------------------------
// GEMM1 via MFMA + fused per-head attention logits. h1 stored as bf16.
// Wave owns 16 rows x 64 cols; no LDS, no barriers.
// D frag: col = lane&15, row = (lane>>4)*4+reg.
// ---------------------------------------------------------------------------
__global__ __launch_bounds__(256) void k_gemm1m(
    const float* __restrict__ x, const uint4* __restrict__ w1f,
    const float* __restrict__ a_src, const float* __restrict__ a_dst,
    unsigned short* __restrict__ h1b, float* __restrict__ als,
    float* __restrict__ ald) {
  const int t = threadIdx.x;
  const int lane = t & 63;
  const int wv = t >> 6;
  const int rb = blockIdx.x * 64 + wv * 16;
  int arow = rb + (lane & 15);
  if (arow >= N_NODES) arow = N_NODES - 1;   // clamp; stores predicated
  const float* aptr = x + (size_t)arow * F_IN + ((lane >> 4) << 3);

  f32x4 acc[4];
#pragma unroll
  for (int i = 0; i < 4; ++i) acc[i] = (f32x4){0.f, 0.f, 0.f, 0.f};

#pragma unroll 4
  for (int s = 0; s < 16; ++s) {
    float4 a0 = *reinterpret_cast<const float4*>(aptr + s * 32);
    float4 a1 = *reinterpret_cast<const float4*>(aptr + s * 32 + 4);
    uint4 b0 = w1f[(s * 4 + 0) * 64 + lane];
    uint4 b1 = w1f[(s * 4 + 1) * 64 + lane];
    uint4 b2 = w1f[(s * 4 + 2) * 64 + lane];
    uint4 b3 = w1f[(s * 4 + 3) * 64 + lane];
    bf16x8 af;
    af[0] = (__bf16)a0.x; af[1] = (__bf16)a0.y;
    af[2] = (__bf16)a0.z; af[3] = (__bf16)a0.w;
    af[4] = (__bf16)a1.x; af[5] = (__bf16)a1.y;
    af[6] = (__bf16)a1.z; af[7] = (__bf16)a1.w;
    acc[0] = __builtin_amdgcn_mfma_f32_16x16x32_bf16(af, __builtin_bit_cast(bf16x8, b0), acc[0], 0, 0, 0);
    acc[1] = __builtin_amdgcn_mfma_f32_16x16x32_bf16(af, __builtin_bit_cast(bf16x8, b1), acc[1], 0, 0, 0);
    acc[2] = __builtin_amdgcn_mfma_f32_16x16x32_bf16(af, __builtin_bit_cast(bf16x8, b2), acc[2], 0, 0, 0);
    acc[3] = __builtin_amdgcn_mfma_f32_16x16x32_bf16(af, __builtin_bit_cast(bf16x8, b3), acc[3], 0, 0, 0);
  }

  const int r0 = rb + ((lane >> 4) << 2);
  const int c = lane & 15;
#pragma unroll
  for (int tt = 0; tt < 4; ++tt) {
#pragma unroll
    for (int i = 0; i < 4; ++i) {
      int r = r0 + i;
      if (r < N_NODES) h1b[(size_t)r * F_H + tt * 16 + c] = f2bf(acc[tt][i]);
    }
  }

  // fused logits
  float asw[4], adw[4];
#pragma unroll
  for (int tt = 0; tt < 4; ++tt) {
    asw[tt] = a_src[tt * 16 + c];
    adw[tt] = a_dst[tt * 16 + c];
  }
  float sp[4][4], dp[4][4];
#pragma unroll
  for (int tt = 0; tt < 4; ++tt)
#pragma unroll
    for (int i = 0; i < 4; ++i) {
      sp[tt][i] = acc[tt][i] * asw[tt];
      dp[tt][i] = acc[tt][i] * adw[tt];
    }
#pragma unroll
  for (int dd = 1; dd < 8; dd <<= 1)
#pragma unroll
    for (int tt = 0; tt < 4; ++tt)
#pragma unroll
      for (int i = 0; i < 4; ++i) {
        sp[tt][i] += __shfl_xor(sp[tt][i], dd);
        dp[tt][i] += __shfl_xor(dp[tt][i], dd);
      }
  if ((c & 7) == 0) {
    const int hb = c >> 3;
#pragma unroll
    for (int i = 0; i < 4; ++i) {
      int r = r0 + i;
      if (r < N_NODES) {
#pragma unroll
        for (int tt = 0; tt < 4; ++tt) {
          als[(size_t)r * HEADS + tt * 2 + hb] = sp[tt][i];
          ald[(size_t)r * HEADS + tt * 2 + hb] = dp[tt][i];
        }
      }
    }
  }
}

// ---------------------------------------------------------------------------
// Layer-1 edge softmax + aggregation + bias + ELU. Wave per node, lane=feature.
// bf16 feature gathers (128B/edge), fp32 accumulate; writes hact as bf16.
// ---------------------------------------------------------------------------
__global__ __launch_bounds__(256) void k_agg1(
    const int* __restrict__ rowstart, const int* __restrict__ csrc,
    const unsigned short* __restrict__ h1b, const float* __restrict__ als,
    const float* __restrict__ ald, const float* __restrict__ b1,
    unsigned short* __restrict__ hactb) {
  int wid = (int)((blockIdx.x * 256 + threadIdx.x) >> 6);
  int lane = threadIdx.x & 63;
  if (wid >= N_NODES) return;
  const int n = wid;
  const int e0 = rowstart[n], e1 = rowstart[n + 1];
  const int hh = lane >> 3;
  const float aldv = ald[(size_t)n * HEADS + hh];

  float denom = 0.f, acc = 0.f;
  int e = e0;
  for (; e + 4 <= e1; e += 4) {
    int s0 = csrc[e], s1 = csrc[e + 1], s2 = csrc[e + 2], s3 = csrc[e + 3];
    float a0 = als[(size_t)s0 * HEADS + hh];
    float a1 = als[(size_t)s1 * HEADS + hh];
    float a2 = als[(size_t)s2 * HEADS + hh];
    float a3 = als[(size_t)s3 * HEADS + hh];
    unsigned short u0 = h1b[(size_t)s0 * F_H + lane];
    unsigned short u1 = h1b[(size_t)s1 * F_H + lane];
    unsigned short u2 = h1b[(size_t)s2 * F_H + lane];
    unsigned short u3 = h1b[(size_t)s3 * F_H + lane];
    float v0 = a0 + aldv; v0 = (v0 > 0.f) ? v0 : NEG * v0;
    float v1 = a1 + aldv; v1 = (v1 > 0.f) ? v1 : NEG * v1;
    float v2 = a2 + aldv; v2 = (v2 > 0.f) ? v2 : NEG * v2;
    float v3 = a3 + aldv; v3 = (v3 > 0.f) ? v3 : NEG * v3;
    float p0 = __expf(v0), p1 = __expf(v1), p2 = __expf(v2), p3 = __expf(v3);
    denom += (p0 + p1) + (p2 + p3);
    acc += p0 * bf2f(u0) + p1 * bf2f(u1) + p2 * bf2f(u2) + p3 * bf2f(u3);
  }
  for (; e < e1; ++e) {
    int s = csrc[e];
    float v = als[(size_t)s * HEADS + hh] + aldv;
    v = (v > 0.f) ? v : NEG * v;
    float p = __expf(v);
    denom += p;
    acc += p * bf2f(h1b[(size_t)s * F_H + lane]);
  }
  float o = acc / denom + b1[lane];
  o = (o > 0.f) ? o : expm1f(o);
  hactb[(size_t)n * F_H + lane] = f2bf(o);
}

// ---------------------------------------------------------------------------
// Layer-2 projection: h2 = hact @ W2 (64x40) + attention logits (1 head).
// bf16 in, bf16 out (logits fp32).
// ---------------------------------------------------------------------------
__global__ __launch_bounds__(256) void k_l2proj(
    const unsigned short* __restrict__ hactb, const float* __restrict__ W2,
    const float* __restrict__ a_src2, const float* __restrict__ a_dst2,
    unsigned short* __restrict__ h2b, float* __restrict__ als2,
    float* __restrict__ ald2) {
  __shared__ float hs[64 * 68];
  __shared__ float w2s[F_H * NC];
  const int t = threadIdx.x;
  const int nb = blockIdx.x * 64;
  {
    int r0 = t >> 3, c8 = t & 7;   // 32 rows/pass x 8 col-groups of 8
#pragma unroll
    for (int i = 0; i < 2; ++i) {
      int r = r0 + i * 32;
      int gr = nb + r;
      u16x8 v = (u16x8)(0);
      if (gr < N_NODES)
        v = *reinterpret_cast<const u16x8*>(&hactb[(size_t)gr * F_H + c8 * 8]);
#pragma unroll
      for (int k = 0; k < 8; ++k) hs[r * 68 + c8 * 8 + k] = bf2f(v[k]);
    }
  }
  for (int i = t; i < F_H * NC; i += 256) w2s[i] = W2[i];
  __syncthreads();

  const int node = t >> 2, cg = t & 3;
  float acc[10];
#pragma unroll
  for (int c = 0; c < 10; ++c) acc[c] = 0.f;
  for (int k = 0; k < F_H; ++k) {
    float xv = hs[node * 68 + k];
#pragma unroll
    for (int c = 0; c < 10; ++c) acc[c] += xv * w2s[k * NC + cg * 10 + c];
  }
  const int gn = nb + node;
  float ps = 0.f, pd = 0.f;
#pragma unroll
  for (int c = 0; c < 10; ++c) {
    ps += acc[c] * a_src2[cg * 10 + c];
    pd += acc[c] * a_dst2[cg * 10 + c];
  }
  ps += __shfl_xor(ps, 1); ps += __shfl_xor(ps, 2);
  pd += __shfl_xor(pd, 1); pd += __shfl_xor(pd, 2);
  if (gn < N_NODES) {
#pragma unroll
    for (int c = 0; c < 10; ++c) h2b[(size_t)gn * NC + cg * 10 + c] = f2bf(acc[c]);
    if (cg == 0) { als2[gn] = ps; ald2[gn] = pd; }
  }
}

// ---------------------------------------------------------------------------
// Layer-2 edge softmax + aggregation + bias + log_softmax. Wave per node.
// bf16 feature gathers (80B/edge).
// ---------------------------------------------------------------------------
__global__ __launch_bounds__(256) void k_agg2(
    const int* __restrict__ rowstart, const int* __restrict__ csrc,
    const unsigned short* __restrict__ h2b, const float* __restrict__ als2,
    const float* __restrict__ ald2, const float* __restrict__ b2,
    float* __restrict__ out) {
  int wid = (int)((blockIdx.x * 256 + threadIdx.x) >> 6);
  int lane = threadIdx.x & 63;
  if (wid >= N_NODES) return;
  const int n = wid;
  const int e0 = rowstart[n], e1 = rowstart[n + 1];
  const float aldv = ald2[n];
  const bool act = (lane < NC);
  const int fl = act ? lane : 0;

  float denom = 0.f, acc = 0.f;
  int e = e0;
  for (; e + 4 <= e1; e += 4) {
    int s0 = csrc[e], s1 = csrc[e + 1], s2 = csrc[e + 2], s3 = csrc[e + 3];
    float a0 = als2[s0], a1 = als2[s1], a2 = als2[s2], a3 = als2[s3];
    unsigned short u0 = h2b[(size_t)s0 * NC + fl];
    unsigned short u1 = h2b[(size_t)s1 * NC + fl];
    unsigned short u2 = h2b[(size_t)s2 * NC + fl];
    unsigned short u3 = h2b[(size_t)s3 * NC + fl];
    float v0 = a0 + aldv; v0 = (v0 > 0.f) ? v0 : NEG * v0;
    float v1 = a1 + aldv; v1 = (v1 > 0.f) ? v1 : NEG * v1;
    float v2 = a2 + aldv; v2 = (v2 > 0.f) ? v2 : NEG * v2;
    float v3 = a3 + aldv; v3 = (v3 > 0.f) ? v3 : NEG * v3;
    float p0 = __expf(v0), p1 = __expf(v1), p2 = __expf(v2), p3 = __expf(v3);
    denom += (p0 + p1) + (p2 + p3);
    acc += p0 * bf2f(u0) + p1 * bf2f(u1) + p2 * bf2f(u2) + p3 * bf2f(u3);
  }
  for (; e < e1; ++e) {
    int s = csrc[e];
    float v = als2[s] + aldv;
    v = (v > 0.f) ? v : NEG * v;
    float p = __expf(v);
    denom += p;
    acc += p * bf2f(h2b[(size_t)s * NC + fl]);
  }
  float o = act ? (acc / denom + b2[lane]) : -1e30f;
  float mx = o;
#pragma unroll
  for (int d = 1; d < 64; d <<= 1) mx = fmaxf(mx, __shfl_xor(mx, d));
  float ex = act ? __expf(o - mx) : 0.f;
  float se = ex;
#pragma unroll
  for (int d = 1; d < 64; d <<= 1) se += __shfl_xor(se, d);
  if (act) out[(size_t)n * NC + lane] = (o - mx) - __logf(se);
}

// ---------------------------------------------------------------------------
extern "C" void kernel_launch(void* const* d_in, const int* in_sizes, int n_in,
                              void* d_out, int out_size, void* d_ws, size_t ws_size,
                              hipStream_t stream) {
  const float* x      = (const float*)d_in[0];
  const int*   ei     = (const int*)d_in[1];
  const float* W1     = (const float*)d_in[2];
  const float* a_src1 = (const float*)d_in[3];
  const float* a_dst1 = (const float*)d_in[4];
  const float* b1     = (const float*)d_in[5];
  const float* W2     = (const float*)d_in[6];
  const float* a_src2 = (const float*)d_in[7];
  const float* a_dst2 = (const float*)d_in[8];
  const float* b2     = (const float*)d_in[9];
  float* out = (float*)d_out;

  char* ws = (char*)d_ws;
  size_t o = 0;
  auto carve = [&](size_t bytes) -> char* {
    char* p = ws + o;
    o = (o + bytes + 255) & ~(size_t)255;
    return p;
  };
  int*   flag     = (int*)carve(256);
  int*   bcnt     = (int*)carve((size_t)NB * 4);
  int*   bstart   = (int*)carve((size_t)(NB + 1) * 4);
  int*   bcur     = (int*)carve((size_t)NB * 4);
  int*   rowstart = (int*)carve((size_t)(N_NODES + 1) * 4);
  unsigned int* inter = (unsigned int*)carve((size_t)E_TOT * 4);
  int*   csrc     = (int*)carve((size_t)E_TOT * 4);
  uint4* w1f      = (uint4*)carve((size_t)4096 * 16);
  unsigned short* h1b   = (unsigned short*)carve((size_t)N_NODES * F_H * 2);
  float* als1     = (float*)carve((size_t)N_NODES * HEADS * 4);
  float* ald1     = (float*)carve((size_t)N_NODES * HEADS * 4);
  unsigned short* hactb = (unsigned short*)carve((size_t)N_NODES * F_H * 2);
  unsigned short* h2b   = (unsigned short*)carve((size_t)N_NODES * NC * 2);
  float* als2     = (float*)carve((size_t)N_NODES * 4);
  float* ald2     = (float*)carve((size_t)N_NODES * 4);
  (void)ws_size; (void)n_in; (void)in_sizes; (void)out_size;

  hipMemsetAsync(bcnt, 0, (size_t)NB * 4, stream);
  k_detect<<<1, 64, 0, stream>>>(ei, flag);
  k_bhist<<<NBLK_E, 256, 0, stream>>>(ei, flag, bcnt);
  k_bscan<<<1, 512, 0, stream>>>(bcnt, bstart, bcur, rowstart);
  k_bfill<<<NBLK_E, 256, 0, stream>>>(ei, flag, bcur, inter);
  k_cfill<<<NB, 256, 0, stream>>>(inter, bstart, rowstart, csrc);

  k_packW<<<16, 256, 0, stream>>>(W1, w1f);
  k_gemm1m<<<(N_NODES + 63) / 64, 256, 0, stream>>>(x, w1f, a_src1, a_dst1, h1b, als1, ald1);
  k_agg1<<<(N_NODES * 64 + 255) / 256, 256, 0, stream>>>(rowstart, csrc, h1b, als1, ald1, b1, hactb);
  k_l2proj<<<(N_NODES + 63) / 64, 256, 0, stream>>>(hactb, W2, a_src2, a_dst2, h2b, als2, ald2);
  k_agg2<<<(N_NODES * 64 + 255) / 256, 256, 0, stream>>>(rowstart, csrc, h2b, als2, ald2, b2, out);
}